// Round 15
// baseline (123.899 us; speedup 1.0000x reference)
//
#include <hip/hip_runtime.h>
#include <stdint.h>
#include <math.h>

#define BB 4
#define SS 1024
#define DD 1024
#define HH 16
#define DHH 64
#define NCLIP 64
#define NCC 129   // 2*CLIP+1
#define NCP 160   // padded bucket count
#define QRSTR 148 // QR row stride in LDS (bf16)
#define M0F 20.0f // fixed softmax max

typedef __bf16 bf16;
typedef __bf16 bf16x8 __attribute__((ext_vector_type(8)));
typedef float f32x4 __attribute__((ext_vector_type(4)));

__device__ __forceinline__ void gload_lds16(const void* g, void* l) {
  __builtin_amdgcn_global_load_lds((const __attribute__((address_space(1))) void*)g,
                                   (__attribute__((address_space(3))) void*)l, 16, 0, 0);
}

// ---------------- batched transpose + pack W: fp32 [K][N] -> bf16 [N][K] ----------------
struct TpArgs { const float* w[4]; bf16* wt[4]; };
__global__ __launch_bounds__(256) void transpose_pack_w(TpArgs args) {
  const float* __restrict__ W = args.w[blockIdx.z];
  bf16* __restrict__ Wt = args.wt[blockIdx.z];
  __shared__ float tile[32][33];
  int tx = threadIdx.x, ty = threadIdx.y;
  int n0 = blockIdx.x * 32, k0 = blockIdx.y * 32;
#pragma unroll
  for (int i = 0; i < 4; i++)
    tile[ty + i * 8][tx] = W[(size_t)(k0 + ty + i * 8) * DD + n0 + tx];
  __syncthreads();
#pragma unroll
  for (int i = 0; i < 4; i++)
    Wt[(size_t)(n0 + ty + i * 8) * DD + k0 + tx] = (bf16)tile[tx][ty + i * 8];
}

// ---------------- batched fp32 -> bf16 convert (8 elems/thread, vlen skip) ----------------
struct CvtArgs { const float* in[3]; bf16* out[3]; int skip[3]; };
__global__ __launch_bounds__(256) void f32_to_bf16_3(CvtArgs args, const int* __restrict__ vlens) {
  const int z = blockIdx.z;
  if (args.skip[z]) {
    int row0 = (blockIdx.x * 2) & 1023;
    int b = (blockIdx.x * 2) >> 10;
    int vl = vlens[b];
    if (vl > 0 && row0 >= vl) return;
  }
  const float* __restrict__ in = args.in[z];
  bf16* __restrict__ out = args.out[z];
  size_t i = ((size_t)blockIdx.x * 256 + threadIdx.x) * 8;
  f32x4 v0 = *(const f32x4*)(in + i);
  f32x4 v1 = *(const f32x4*)(in + i + 4);
  bf16x8 o;
#pragma unroll
  for (int j = 0; j < 4; j++) { o[j] = (bf16)v0[j]; o[j + 4] = (bf16)v1[j]; }
  *(bf16x8*)(out + i) = o;
}

// ---------------- 128x128 bf16 GEMM (m97-style), gload_lds staging, BK=32 ----------------
struct GemmArgs { const bf16* a[3]; const bf16* bt[3]; void* c[3]; float sc[3]; int skip[3]; };
template <bool SPLIT>
__global__ __launch_bounds__(256) void gemm128(GemmArgs args, const int* __restrict__ vlens) {
  const int z = blockIdx.z;
  const int m0 = blockIdx.y * 128, n0 = blockIdx.x * 128;
  if (args.skip[z]) {
    int vl = vlens[m0 >> 10];
    if (vl > 0 && (m0 & 1023) >= vl) return;
  }
  const bf16* __restrict__ A  = args.a[z];
  const bf16* __restrict__ Bt = args.bt[z];
  void* __restrict__ Cv = args.c[z];
  const float scale = args.sc[z];
  __shared__ __align__(16) bf16 As[128][32];
  __shared__ __align__(16) bf16 Bs[128][32];
  const int tid = threadIdx.x, lane = tid & 63, wv = tid >> 6;
  const int wr = wv >> 1, wc = wv & 1;
  const int l15 = lane & 15, l4 = lane >> 4;
  const int srow = lane >> 2, scol = (lane & 3) * 8;
  f32x4 z4 = {0.f, 0.f, 0.f, 0.f};
  f32x4 acc[4][4];
#pragma unroll
  for (int i = 0; i < 4; i++)
#pragma unroll
    for (int j = 0; j < 4; j++) acc[i][j] = z4;

  for (int k0 = 0; k0 < DD; k0 += 32) {
    gload_lds16(A  + (size_t)(m0 + wv * 16 + srow) * DD + k0 + scol,      &As[wv * 16][0]);
    gload_lds16(A  + (size_t)(m0 + 64 + wv * 16 + srow) * DD + k0 + scol, &As[64 + wv * 16][0]);
    gload_lds16(Bt + (size_t)(n0 + wv * 16 + srow) * DD + k0 + scol,      &Bs[wv * 16][0]);
    gload_lds16(Bt + (size_t)(n0 + 64 + wv * 16 + srow) * DD + k0 + scol, &Bs[64 + wv * 16][0]);
    __syncthreads();
    bf16x8 af[4], bfv[4];
#pragma unroll
    for (int i = 0; i < 4; i++) {
      af[i]  = *(const bf16x8*)&As[wr * 64 + i * 16 + l15][l4 * 8];
      bfv[i] = *(const bf16x8*)&Bs[wc * 64 + i * 16 + l15][l4 * 8];
    }
#pragma unroll
    for (int mi = 0; mi < 4; mi++)
#pragma unroll
      for (int ni = 0; ni < 4; ni++)
        acc[mi][ni] = __builtin_amdgcn_mfma_f32_16x16x32_bf16(af[mi], bfv[ni], acc[mi][ni], 0, 0, 0);
    __syncthreads();
  }
#pragma unroll
  for (int mi = 0; mi < 4; mi++)
#pragma unroll
    for (int ni = 0; ni < 4; ni++)
#pragma unroll
      for (int r = 0; r < 4; r++) {
        int m = m0 + wr * 64 + mi * 16 + l4 * 4 + r;
        int n = n0 + wc * 64 + ni * 16 + l15;
        float val = acc[mi][ni][r] * scale;
        if (SPLIT) {
          ((bf16*)Cv)[((((size_t)(m >> 10) * HH + (n >> 6)) * SS) + (m & 1023)) * DHH + (n & 63)] =
              (bf16)val;
        } else {
          ((float*)Cv)[(size_t)m * DD + n] = val;
        }
      }
}

// ---------------- 64x128 bf16 GEMM for the final projection ----------------
__global__ __launch_bounds__(256) void gemm_bf16_final(const bf16* __restrict__ A,
                                                       const bf16* __restrict__ Bt,
                                                       float* __restrict__ C) {
  __shared__ __align__(16) bf16 As[64][32];
  __shared__ __align__(16) bf16 Bs[128][32];
  const int tid = threadIdx.x, lane = tid & 63, wv = tid >> 6;
  const int l15 = lane & 15, l4 = lane >> 4;
  const int m0 = blockIdx.y * 64, n0 = blockIdx.x * 128;
  const int srow = lane >> 2, scol = (lane & 3) * 8;
  f32x4 z4 = {0.f, 0.f, 0.f, 0.f};
  f32x4 acc[4][2];
#pragma unroll
  for (int i = 0; i < 4; i++) { acc[i][0] = z4; acc[i][1] = z4; }

  for (int k0 = 0; k0 < DD; k0 += 32) {
    gload_lds16(A + (size_t)(m0 + wv * 16 + srow) * DD + k0 + scol, &As[wv * 16][0]);
    gload_lds16(Bt + (size_t)(n0 + wv * 32 + srow) * DD + k0 + scol, &Bs[wv * 32][0]);
    gload_lds16(Bt + (size_t)(n0 + wv * 32 + 16 + srow) * DD + k0 + scol, &Bs[wv * 32 + 16][0]);
    __syncthreads();
    bf16x8 af[4], bfv[2];
#pragma unroll
    for (int i = 0; i < 4; i++) af[i] = *(const bf16x8*)&As[i * 16 + l15][l4 * 8];
#pragma unroll
    for (int i = 0; i < 2; i++) bfv[i] = *(const bf16x8*)&Bs[wv * 32 + i * 16 + l15][l4 * 8];
#pragma unroll
    for (int mi = 0; mi < 4; mi++)
#pragma unroll
      for (int ni = 0; ni < 2; ni++)
        acc[mi][ni] = __builtin_amdgcn_mfma_f32_16x16x32_bf16(af[mi], bfv[ni], acc[mi][ni], 0, 0, 0);
    __syncthreads();
  }
#pragma unroll
  for (int mi = 0; mi < 4; mi++)
#pragma unroll
    for (int ni = 0; ni < 2; ni++)
#pragma unroll
      for (int r = 0; r < 4; r++) {
        int m = m0 + mi * 16 + l4 * 4 + r;
        int n = n0 + wv * 32 + ni * 16 + l15;
        C[(size_t)m * DD + n] = acc[mi][ni][r];
      }
}

// ---------------- Vh [bh][s][d] -> VhT [bh][d][s]  (vlen skip) ----------------
__global__ __launch_bounds__(256) void vh_transpose(const bf16* __restrict__ Vh,
                                                    bf16* __restrict__ VhT,
                                                    const int* __restrict__ vlens) {
  __shared__ bf16 til[64][65];
  int bh = blockIdx.y;
  int s0 = blockIdx.x * 64;
  int vl = vlens[bh >> 4];
  if (vl > 0 && s0 >= vl + 64) return;   // attn (KVBLK=64) reads V cols < roundup64(vl)
  const bf16* src = Vh + (size_t)bh * SS * DHH + (size_t)s0 * DHH;
  for (int i = threadIdx.x; i < 64 * 64; i += 256) {
    int r = i >> 6, cc = i & 63;
    til[r][cc] = src[(size_t)r * DHH + cc];
  }
  __syncthreads();
  bf16* dst = VhT + (size_t)bh * DHH * SS + s0;
  for (int i = threadIdx.x; i < 64 * 64; i += 256) {
    int d = i >> 6, cc = i & 63;
    dst[(size_t)d * SS + cc] = til[cc][d];
  }
}

// ------- prep tables: rvT bf16 [64][160] (rpr_v^T, padded) + rkP bf16 [144][64] -------
__global__ void prep_tables(const float* __restrict__ rpr_v, const float* __restrict__ rpr_k,
                            bf16* __restrict__ rvT, bf16* __restrict__ rkP) {
  int i = blockIdx.x * 256 + threadIdx.x;
  if (i < DHH * NCP) {
    int d = i / NCP, c = i - d * NCP;
    rvT[i] = (c < NCC) ? (bf16)rpr_v[(size_t)c * DHH + d] : (bf16)0.f;
  }
  if (i < 144 * 64) {
    rkP[i] = (i < NCC * DHH) ? (bf16)rpr_k[i] : (bf16)0.f;
  }
}

// ---- fused attention, KVBLK=64: shared K tile (LDS), direct V, 2 barriers per 64 keys ----
// Ks[64][64] staged via global_load_lds with pre-swizzled source (chunk ^= row&7).
// Per tile: 8 QK MFMA + 4-sub softmax + 8 PV MFMA (V direct from global, L2-hot).
// Per-wave arena (11264 B): [0,4736) QRs 16x148 | [4736,8832) SBand 16x128 f16 |
// [8832,11136) Pl 16x72 bf16 -> li/a0/a128 floats in epilogue; AW 16x168 overlays [0,5376).
__global__ __launch_bounds__(256, 3) void attn_mfma(
    const bf16* __restrict__ Qh, const bf16* __restrict__ Kh, const bf16* __restrict__ VhT,
    const bf16* __restrict__ rkP, const int* __restrict__ valid_lens,
    const bf16* __restrict__ rvT, bf16* __restrict__ Obh) {
  __shared__ __align__(16) bf16 Ks[64][64];
  __shared__ __align__(16) char arena[4][11264];
  const int tid = threadIdx.x, lane = tid & 63, w = tid >> 6;
  const int l15 = lane & 15, l4 = lane >> 4;
  const int b = blockIdx.z, h = blockIdx.y, bh = b * HH + h;
  const int q0 = blockIdx.x * 64 + w * 16;
  const int vlen = valid_lens[b];
  const float mval = (vlen == 0) ? 0.f : -30000.f;
  char* base = arena[w];
  bf16* QRs = (bf16*)base;                      // [16][148]
  _Float16* SBand = (_Float16*)(base + 4736);   // [16][128]
  bf16* Pl = (bf16*)(base + 8832);              // [16][72]

  const bf16* Qbase = Qh + ((size_t)bh * SS + q0) * DHH;
  bf16x8 qa0 = *(const bf16x8*)(Qbase + (size_t)l15 * DHH + l4 * 8);
  bf16x8 qa1 = *(const bf16x8*)(Qbase + (size_t)l15 * DHH + 32 + l4 * 8);
  const bf16* Kbase = Kh + (size_t)bh * SS * DHH;
  const bf16* Vbase = VhT + (size_t)bh * DHH * SS;
  f32x4 z = {0.f, 0.f, 0.f, 0.f};

  // ---- QR prologue: QRs[q][c] = Q[q]·rpr_k[c] via 9x2 MFMA on pre-packed bf16 rkP ----
#pragma unroll
  for (int ni = 0; ni < 9; ni++) {
    const bf16* rp = rkP + (size_t)(ni * 16 + l15) * DHH + l4 * 8;
    bf16x8 b0 = *(const bf16x8*)(rp);
    bf16x8 b1 = *(const bf16x8*)(rp + 32);
    f32x4 acc = __builtin_amdgcn_mfma_f32_16x16x32_bf16(qa0, b0, z, 0, 0, 0);
    acc = __builtin_amdgcn_mfma_f32_16x16x32_bf16(qa1, b1, acc, 0, 0, 0);
#pragma unroll
    for (int r = 0; r < 4; r++)
      QRs[(l4 * 4 + r) * QRSTR + ni * 16 + l15] = (bf16)acc[r];
  }
  {
    _Float16 ninf = (_Float16)(-65504.f);
    for (int i = lane; i < 16 * 128; i += 64) SBand[i] = ninf;
  }

  float biasLo[4], biasHi[4];
#pragma unroll
  for (int r = 0; r < 4; r++) {
    biasLo[r] = (float)QRs[(l4 * 4 + r) * QRSTR + 0];
    biasHi[r] = (float)QRs[(l4 * 4 + r) * QRSTR + 128];
  }

  float l_lane[4], slo[4], shi[4];
#pragma unroll
  for (int r = 0; r < 4; r++) { l_lane[r] = 0.f; slo[r] = 0.f; shi[r] = 0.f; }
  f32x4 acco[4];
#pragma unroll
  for (int i = 0; i < 4; i++) acco[i] = z;

  // K staging constants (source pre-swizzle chunk ^= row&7; LDS linear) + read offsets
  const int krow = w * 16 + (lane >> 3);          // issue0 rows; issue1 = +8 (same row&7)
  const int kch  = ((lane & 7) ^ (krow & 7)) * 8;
  const int ksw0 = (l4 ^ (l15 & 7)) * 8;
  const int ksw1 = ((l4 + 4) ^ (l15 & 7)) * 8;

  // bounds (64-granular): tail [kfb, kte); band [bs, be) for this wave's q0
  const int kfb = (vlen > 0) ? (vlen & ~63) : 0;
  const int kte = (vlen > 0) ? ((vlen + 63) & ~63) : SS;
  int bs = q0 - 126; bs = (bs < 0) ? 0 : ((bs + 63) & ~63);
  int be = (q0 + 79 + 63) & ~63; if (be > SS) be = SS;

  for (int ks = 0; ks < kte; ks += 64) {
    gload_lds16(Kbase + (size_t)(ks + krow) * DHH + kch, &Ks[w * 16][0]);
    gload_lds16(Kbase + (size_t)(ks + krow + 8) * DHH + kch, &Ks[w * 16 + 8][0]);
    __syncthreads();
    f32x4 aa[4];
#pragma unroll
    for (int sub = 0; sub < 4; sub++) {
      bf16x8 kf0 = *(const bf16x8*)&Ks[sub * 16 + l15][ksw0];
      bf16x8 kf1 = *(const bf16x8*)&Ks[sub * 16 + l15][ksw1];
      f32x4 a = __builtin_amdgcn_mfma_f32_16x16x32_bf16(qa0, kf0, z, 0, 0, 0);
      aa[sub] = __builtin_amdgcn_mfma_f32_16x16x32_bf16(qa1, kf1, a, 0, 0, 0);
    }

    if (ks >= kfb) {
      // masked tail (<=1 tile for vlen>0; all tiles for vlen==0)
      const int rel = ks - q0;
      const int mode = (rel <= -127) ? 0 : (rel >= 79) ? 1 : 2;
#pragma unroll
      for (int sub = 0; sub < 4; sub++) {
        const f32x4 a = aa[sub];
        const int kg = ks + sub * 16 + l15;
        const bool msk = (kg >= vlen);
        if (mode == 0) {
#pragma unroll
          for (int r = 0; r < 4; r++) {
            float s = msk ? mval : (a[r] + biasLo[r]);
            float p = __expf(s - M0F);
            l_lane[r] += p; slo[r] += p;
            Pl[(l4 * 4 + r) * 72 + sub * 16 + l15] = (bf16)p;
          }
        } else if (mode == 1) {
#pragma unroll
          for (int r = 0; r < 4; r++) {
            float s = msk ? mval : (a[r] + biasHi[r]);
            float p = __expf(s - M0F);
            l_lane[r] += p; shi[r] += p;
            Pl[(l4 * 4 + r) * 72 + sub * 16 + l15] = (bf16)p;
          }
        } else {
#pragma unroll
          for (int r = 0; r < 4; r++) {
            const int qloc = l4 * 4 + r;
            int dlt = kg - q0 - qloc;
            int c = (dlt < -NCLIP ? -NCLIP : (dlt > NCLIP ? NCLIP : dlt)) + NCLIP;
            float s = a[r] + (float)QRs[qloc * QRSTR + c];
            if (msk) s = mval;
            if (dlt > -64 && dlt < 64) SBand[qloc * 128 + dlt + 63] = (_Float16)s;
            float p = __expf(s - M0F);
            l_lane[r] += p;
            slo[r] += (dlt <= -64) ? p : 0.f;
            shi[r] += (dlt >= 64) ? p : 0.f;
            Pl[qloc * 72 + sub * 16 + l15] = (bf16)p;
          }
        }
      }
    } else if (ks < bs) {
      // lo tiles (all dlt <= -64, unmasked)
#pragma unroll
      for (int sub = 0; sub < 4; sub++) {
        const f32x4 a = aa[sub];
#pragma unroll
        for (int r = 0; r < 4; r++) {
          float p = __expf(a[r] + biasLo[r] - M0F);
          l_lane[r] += p; slo[r] += p;
          Pl[(l4 * 4 + r) * 72 + sub * 16 + l15] = (bf16)p;
        }
      }
    } else if (ks < be) {
      // band tiles (unmasked, full body)
#pragma unroll
      for (int sub = 0; sub < 4; sub++) {
        const f32x4 a = aa[sub];
        const int kg = ks + sub * 16 + l15;
#pragma unroll
        for (int r = 0; r < 4; r++) {
          const int qloc = l4 * 4 + r;
          int dlt = kg - q0 - qloc;
          int c = (dlt < -NCLIP ? -NCLIP : (dlt > NCLIP ? NCLIP : dlt)) + NCLIP;
          float s = a[r] + (float)QRs[qloc * QRSTR + c];
          if (dlt > -64 && dlt < 64) SBand[qloc * 128 + dlt + 63] = (_Float16)s;
          float p = __expf(s - M0F);
          l_lane[r] += p;
          slo[r] += (dlt <= -64) ? p : 0.f;
          shi[r] += (dlt >= 64) ? p : 0.f;
          Pl[qloc * 72 + sub * 16 + l15] = (bf16)p;
        }
      }
    } else {
      // hi tiles (all dlt >= 64, unmasked)
#pragma unroll
      for (int sub = 0; sub < 4; sub++) {
        const f32x4 a = aa[sub];
#pragma unroll
        for (int r = 0; r < 4; r++) {
          float p = __expf(a[r] + biasHi[r] - M0F);
          l_lane[r] += p; shi[r] += p;
          Pl[(l4 * 4 + r) * 72 + sub * 16 + l15] = (bf16)p;
        }
      }
    }

    bf16x8 pa0 = *(const bf16x8*)&Pl[l15 * 72 + l4 * 8];
    bf16x8 pa1 = *(const bf16x8*)&Pl[l15 * 72 + 32 + l4 * 8];
#pragma unroll
    for (int ni = 0; ni < 4; ni++) {
      const bf16* vp = Vbase + (size_t)(ni * 16 + l15) * SS + ks + l4 * 8;
      acco[ni] = __builtin_amdgcn_mfma_f32_16x16x32_bf16(pa0, *(const bf16x8*)(vp), acco[ni], 0, 0, 0);
      acco[ni] = __builtin_amdgcn_mfma_f32_16x16x32_bf16(pa1, *(const bf16x8*)(vp + 32), acco[ni], 0, 0, 0);
    }
    __syncthreads();
  }

  // ---- epilogue step 1: reduce l/slo/shi; stash li, aw0, aw128 ----
  float* li_s   = (float*)(base + 8832);
  float* a0_s   = (float*)(base + 8896);
  float* a128_s = (float*)(base + 8960);
  float li_r[4];
#pragma unroll
  for (int r = 0; r < 4; r++) {
    const int qloc = l4 * 4 + r;
    float lt = l_lane[r], so = slo[r], sh = shi[r];
    lt += __shfl_xor(lt, 1, 64); so += __shfl_xor(so, 1, 64); sh += __shfl_xor(sh, 1, 64);
    lt += __shfl_xor(lt, 2, 64); so += __shfl_xor(so, 2, 64); sh += __shfl_xor(sh, 2, 64);
    lt += __shfl_xor(lt, 4, 64); so += __shfl_xor(so, 4, 64); sh += __shfl_xor(sh, 4, 64);
    lt += __shfl_xor(lt, 8, 64); so += __shfl_xor(so, 8, 64); sh += __shfl_xor(sh, 8, 64);
    float li = 1.f / lt;
    li_r[r] = li;
    if (l15 == 0) { li_s[qloc] = li; a0_s[qloc] = so * li; a128_s[qloc] = sh * li; }
  }
  // ---- step 2: materialize AW 16x168 bf16 at arena[0] ----
  bf16* AWs = (bf16*)base;
  for (int row = 0; row < 16; row++) {
    float li = li_s[row], a0 = a0_s[row], a128 = a128_s[row];
#pragma unroll
    for (int j = 0; j < 3; j++) {
      int c = lane + 64 * j;
      if (c < 160) {
        float val;
        if (c == 0) val = a0;
        else if (c == 128) val = a128;
        else if (c < 128) val = __expf((float)SBand[row * 128 + c - 1] - M0F) * li;
        else val = 0.f;
        AWs[row * 168 + c] = (bf16)val;
      }
    }
  }
  // ---- step 3: acc2 = AW @ rpr_v ----
  f32x4 acc2[4];
#pragma unroll
  for (int i = 0; i < 4; i++) acc2[i] = z;
#pragma unroll
  for (int kk = 0; kk < 5; kk++) {
    bf16x8 af = *(const bf16x8*)&AWs[l15 * 168 + kk * 32 + l4 * 8];
#pragma unroll
    for (int ni = 0; ni < 4; ni++) {
      bf16x8 bv = *(const bf16x8*)(rvT + (size_t)(ni * 16 + l15) * NCP + kk * 32 + l4 * 8);
      acc2[ni] = __builtin_amdgcn_mfma_f32_16x16x32_bf16(af, bv, acc2[ni], 0, 0, 0);
    }
  }
  // ---- step 4: write Obh bf16 ----
#pragma unroll
  for (int ni = 0; ni < 4; ni++)
#pragma unroll
    for (int r = 0; r < 4; r++) {
      int qg = q0 + l4 * 4 + r;
      Obh[((size_t)b * SS + qg) * DD + h * DHH + ni * 16 + l15] =
          (bf16)(acco[ni][r] * li_r[r] + acc2[ni][r]);
    }
}

extern "C" void kernel_launch(void* const* d_in, const int* in_sizes, int n_in,
                              void* d_out, int out_size, void* d_ws, size_t ws_size,
                              hipStream_t stream) {
  (void)in_sizes; (void)n_in; (void)out_size; (void)ws_size;
  const float* queries = (const float*)d_in[0];
  const float* keys    = (const float*)d_in[1];
  const float* values  = (const float*)d_in[2];
  const int*   vlens   = (const int*)d_in[3];
  const float* Wq = (const float*)d_in[4];
  const float* Wk = (const float*)d_in[5];
  const float* Wv = (const float*)d_in[6];
  const float* Wo = (const float*)d_in[7];
  const float* rpr_k = (const float*)d_in[8];
  const float* rpr_v = (const float*)d_in[9];

  char* ws = (char*)d_ws;
  const size_t MB = 1024 * 1024;
  bf16* Wtq  = (bf16*)(ws + 0 * MB);
  bf16* Wtk  = (bf16*)(ws + 2 * MB);
  bf16* Wtv  = (bf16*)(ws + 4 * MB);
  bf16* Wto  = (bf16*)(ws + 6 * MB);
  bf16* Qh   = (bf16*)(ws + 8 * MB);    // head-split, scaled 0.125
  bf16* Kh   = (bf16*)(ws + 16 * MB);
  bf16* Vh   = (bf16*)(ws + 24 * MB);
  bf16* VhT  = (bf16*)(ws + 32 * MB);
  bf16* Qb   = (bf16*)(ws + 40 * MB);
  bf16* Kb   = (bf16*)(ws + 48 * MB);
  bf16* Vb   = (bf16*)(ws + 56 * MB);
  bf16* Obh  = (bf16*)(ws + 64 * MB);   // 8 MB
  bf16* rvT  = (bf16*)(ws + 72 * MB);   // 20 KB
  bf16* rkP  = (bf16*)(ws + 73 * MB);   // 18 KB

  TpArgs tp; tp.w[0] = Wq; tp.w[1] = Wk; tp.w[2] = Wv; tp.w[3] = Wo;
  tp.wt[0] = Wtq; tp.wt[1] = Wtk; tp.wt[2] = Wtv; tp.wt[3] = Wto;
  transpose_pack_w<<<dim3(32, 32, 4), dim3(32, 8), 0, stream>>>(tp);

  CvtArgs cv; cv.in[0] = queries; cv.in[1] = keys; cv.in[2] = values;
  cv.out[0] = Qb; cv.out[1] = Kb; cv.out[2] = Vb;
  cv.skip[0] = 0; cv.skip[1] = 1; cv.skip[2] = 1;
  f32_to_bf16_3<<<dim3(2048, 1, 3), 256, 0, stream>>>(cv, vlens);

  GemmArgs gp;
  gp.a[0] = Qb; gp.a[1] = Kb; gp.a[2] = Vb;
  gp.bt[0] = Wtq; gp.bt[1] = Wtk; gp.bt[2] = Wtv;
  gp.c[0] = (void*)Qh; gp.c[1] = (void*)Kh; gp.c[2] = (void*)Vh;
  gp.sc[0] = 0.125f; gp.sc[1] = 1.0f; gp.sc[2] = 1.0f;
  gp.skip[0] = 0; gp.skip[1] = 1; gp.skip[2] = 1;
  gemm128<true><<<dim3(8, 32, 3), 256, 0, stream>>>(gp, vlens);

  vh_transpose<<<dim3(16, 64), 256, 0, stream>>>(Vh, VhT, vlens);
  prep_tables<<<dim3(40), 256, 0, stream>>>(rpr_v, rpr_k, rvT, rkP);
  attn_mfma<<<dim3(16, HH, BB), 256, 0, stream>>>(Qh, Kh, VhT, rkP, vlens, rvT, Obh);
  gemm_bf16_final<<<dim3(8, 64), 256, 0, stream>>>(Obh, Wto, (float*)d_out);
}

// Round 16
// 122.371 us; speedup vs baseline: 1.0125x; 1.0125x over previous
//
#include <hip/hip_runtime.h>
#include <stdint.h>
#include <math.h>

#define BB 4
#define SS 1024
#define DD 1024
#define HH 16
#define DHH 64
#define NCLIP 64
#define NCC 129   // 2*CLIP+1
#define NCP 160   // padded bucket count
#define QRSTR 148 // QR row stride in LDS (bf16)
#define M0F 20.0f // fixed softmax max

typedef __bf16 bf16;
typedef __bf16 bf16x8 __attribute__((ext_vector_type(8)));
typedef float f32x4 __attribute__((ext_vector_type(4)));

__device__ __forceinline__ void gload_lds16(const void* g, void* l) {
  __builtin_amdgcn_global_load_lds((const __attribute__((address_space(1))) void*)g,
                                   (__attribute__((address_space(3))) void*)l, 16, 0, 0);
}

// ---------------- batched transpose + pack W: fp32 [K][N] -> bf16 [N][K] ----------------
struct TpArgs { const float* w[4]; bf16* wt[4]; };
__global__ __launch_bounds__(256) void transpose_pack_w(TpArgs args) {
  const float* __restrict__ W = args.w[blockIdx.z];
  bf16* __restrict__ Wt = args.wt[blockIdx.z];
  __shared__ float tile[32][33];
  int tx = threadIdx.x, ty = threadIdx.y;
  int n0 = blockIdx.x * 32, k0 = blockIdx.y * 32;
#pragma unroll
  for (int i = 0; i < 4; i++)
    tile[ty + i * 8][tx] = W[(size_t)(k0 + ty + i * 8) * DD + n0 + tx];
  __syncthreads();
#pragma unroll
  for (int i = 0; i < 4; i++)
    Wt[(size_t)(n0 + ty + i * 8) * DD + k0 + tx] = (bf16)tile[tx][ty + i * 8];
}

// ---------------- batched fp32 -> bf16 convert (8 elems/thread, vlen skip) ----------------
struct CvtArgs { const float* in[3]; bf16* out[3]; int skip[3]; };
__global__ __launch_bounds__(256) void f32_to_bf16_3(CvtArgs args, const int* __restrict__ vlens) {
  const int z = blockIdx.z;
  if (args.skip[z]) {
    int row0 = (blockIdx.x * 2) & 1023;
    int b = (blockIdx.x * 2) >> 10;
    int vl = vlens[b];
    if (vl > 0 && row0 >= vl) return;
  }
  const float* __restrict__ in = args.in[z];
  bf16* __restrict__ out = args.out[z];
  size_t i = ((size_t)blockIdx.x * 256 + threadIdx.x) * 8;
  f32x4 v0 = *(const f32x4*)(in + i);
  f32x4 v1 = *(const f32x4*)(in + i + 4);
  bf16x8 o;
#pragma unroll
  for (int j = 0; j < 4; j++) { o[j] = (bf16)v0[j]; o[j + 4] = (bf16)v1[j]; }
  *(bf16x8*)(out + i) = o;
}

// ---------------- 128x128 bf16 GEMM (m97-style), gload_lds staging, BK=32 ----------------
struct GemmArgs { const bf16* a[3]; const bf16* bt[3]; void* c[3]; float sc[3]; int skip[3]; };
template <bool SPLIT>
__global__ __launch_bounds__(256) void gemm128(GemmArgs args, const int* __restrict__ vlens) {
  const int z = blockIdx.z;
  const int m0 = blockIdx.y * 128, n0 = blockIdx.x * 128;
  if (args.skip[z]) {
    int vl = vlens[m0 >> 10];
    if (vl > 0 && (m0 & 1023) >= vl) return;
  }
  const bf16* __restrict__ A  = args.a[z];
  const bf16* __restrict__ Bt = args.bt[z];
  void* __restrict__ Cv = args.c[z];
  const float scale = args.sc[z];
  __shared__ __align__(16) bf16 As[128][32];
  __shared__ __align__(16) bf16 Bs[128][32];
  const int tid = threadIdx.x, lane = tid & 63, wv = tid >> 6;
  const int wr = wv >> 1, wc = wv & 1;
  const int l15 = lane & 15, l4 = lane >> 4;
  const int srow = lane >> 2, scol = (lane & 3) * 8;
  f32x4 z4 = {0.f, 0.f, 0.f, 0.f};
  f32x4 acc[4][4];
#pragma unroll
  for (int i = 0; i < 4; i++)
#pragma unroll
    for (int j = 0; j < 4; j++) acc[i][j] = z4;

  for (int k0 = 0; k0 < DD; k0 += 32) {
    gload_lds16(A  + (size_t)(m0 + wv * 16 + srow) * DD + k0 + scol,      &As[wv * 16][0]);
    gload_lds16(A  + (size_t)(m0 + 64 + wv * 16 + srow) * DD + k0 + scol, &As[64 + wv * 16][0]);
    gload_lds16(Bt + (size_t)(n0 + wv * 16 + srow) * DD + k0 + scol,      &Bs[wv * 16][0]);
    gload_lds16(Bt + (size_t)(n0 + 64 + wv * 16 + srow) * DD + k0 + scol, &Bs[64 + wv * 16][0]);
    __syncthreads();
    bf16x8 af[4], bfv[4];
#pragma unroll
    for (int i = 0; i < 4; i++) {
      af[i]  = *(const bf16x8*)&As[wr * 64 + i * 16 + l15][l4 * 8];
      bfv[i] = *(const bf16x8*)&Bs[wc * 64 + i * 16 + l15][l4 * 8];
    }
#pragma unroll
    for (int mi = 0; mi < 4; mi++)
#pragma unroll
      for (int ni = 0; ni < 4; ni++)
        acc[mi][ni] = __builtin_amdgcn_mfma_f32_16x16x32_bf16(af[mi], bfv[ni], acc[mi][ni], 0, 0, 0);
    __syncthreads();
  }
#pragma unroll
  for (int mi = 0; mi < 4; mi++)
#pragma unroll
    for (int ni = 0; ni < 4; ni++)
#pragma unroll
      for (int r = 0; r < 4; r++) {
        int m = m0 + wr * 64 + mi * 16 + l4 * 4 + r;
        int n = n0 + wc * 64 + ni * 16 + l15;
        float val = acc[mi][ni][r] * scale;
        if (SPLIT) {
          ((bf16*)Cv)[((((size_t)(m >> 10) * HH + (n >> 6)) * SS) + (m & 1023)) * DHH + (n & 63)] =
              (bf16)val;
        } else {
          ((float*)Cv)[(size_t)m * DD + n] = val;
        }
      }
}

// ------- final projection: 128x128 gemm, XCD-bijective swizzle on M-blocks, float out -------
__global__ __launch_bounds__(256) void gemm_final128(const bf16* __restrict__ A,
                                                     const bf16* __restrict__ Bt,
                                                     float* __restrict__ C) {
  // 32 M-blocks, 8 XCDs: bijective swizzle y' = (y&7)*4 + (y>>3)
  const int my = ((int)blockIdx.y & 7) * 4 + ((int)blockIdx.y >> 3);
  const int m0 = my * 128, n0 = blockIdx.x * 128;
  __shared__ __align__(16) bf16 As[128][32];
  __shared__ __align__(16) bf16 Bs[128][32];
  const int tid = threadIdx.x, lane = tid & 63, wv = tid >> 6;
  const int wr = wv >> 1, wc = wv & 1;
  const int l15 = lane & 15, l4 = lane >> 4;
  const int srow = lane >> 2, scol = (lane & 3) * 8;
  f32x4 z4 = {0.f, 0.f, 0.f, 0.f};
  f32x4 acc[4][4];
#pragma unroll
  for (int i = 0; i < 4; i++)
#pragma unroll
    for (int j = 0; j < 4; j++) acc[i][j] = z4;

  for (int k0 = 0; k0 < DD; k0 += 32) {
    gload_lds16(A  + (size_t)(m0 + wv * 16 + srow) * DD + k0 + scol,      &As[wv * 16][0]);
    gload_lds16(A  + (size_t)(m0 + 64 + wv * 16 + srow) * DD + k0 + scol, &As[64 + wv * 16][0]);
    gload_lds16(Bt + (size_t)(n0 + wv * 16 + srow) * DD + k0 + scol,      &Bs[wv * 16][0]);
    gload_lds16(Bt + (size_t)(n0 + 64 + wv * 16 + srow) * DD + k0 + scol, &Bs[64 + wv * 16][0]);
    __syncthreads();
    bf16x8 af[4], bfv[4];
#pragma unroll
    for (int i = 0; i < 4; i++) {
      af[i]  = *(const bf16x8*)&As[wr * 64 + i * 16 + l15][l4 * 8];
      bfv[i] = *(const bf16x8*)&Bs[wc * 64 + i * 16 + l15][l4 * 8];
    }
#pragma unroll
    for (int mi = 0; mi < 4; mi++)
#pragma unroll
      for (int ni = 0; ni < 4; ni++)
        acc[mi][ni] = __builtin_amdgcn_mfma_f32_16x16x32_bf16(af[mi], bfv[ni], acc[mi][ni], 0, 0, 0);
    __syncthreads();
  }
#pragma unroll
  for (int mi = 0; mi < 4; mi++)
#pragma unroll
    for (int ni = 0; ni < 4; ni++)
#pragma unroll
      for (int r = 0; r < 4; r++) {
        int m = m0 + wr * 64 + mi * 16 + l4 * 4 + r;
        int n = n0 + wc * 64 + ni * 16 + l15;
        C[(size_t)m * DD + n] = acc[mi][ni][r];
      }
}

// ---------------- Vh [bh][s][d] -> VhT [bh][d][s]  (vlen skip) ----------------
__global__ __launch_bounds__(256) void vh_transpose(const bf16* __restrict__ Vh,
                                                    bf16* __restrict__ VhT,
                                                    const int* __restrict__ vlens) {
  __shared__ bf16 til[64][65];
  int bh = blockIdx.y;
  int s0 = blockIdx.x * 64;
  int vl = vlens[bh >> 4];
  if (vl > 0 && s0 >= vl + 32) return;
  const bf16* src = Vh + (size_t)bh * SS * DHH + (size_t)s0 * DHH;
  for (int i = threadIdx.x; i < 64 * 64; i += 256) {
    int r = i >> 6, cc = i & 63;
    til[r][cc] = src[(size_t)r * DHH + cc];
  }
  __syncthreads();
  bf16* dst = VhT + (size_t)bh * DHH * SS + s0;
  for (int i = threadIdx.x; i < 64 * 64; i += 256) {
    int d = i >> 6, cc = i & 63;
    dst[(size_t)d * SS + cc] = til[cc][d];
  }
}

// ------- prep tables: rvT bf16 [64][160] (rpr_v^T, padded) + rkP bf16 [144][64] -------
__global__ void prep_tables(const float* __restrict__ rpr_v, const float* __restrict__ rpr_k,
                            bf16* __restrict__ rvT, bf16* __restrict__ rkP) {
  int i = blockIdx.x * 256 + threadIdx.x;
  if (i < DHH * NCP) {
    int d = i / NCP, c = i - d * NCP;
    rvT[i] = (c < NCC) ? (bf16)rpr_v[(size_t)c * DHH + d] : (bf16)0.f;
  }
  if (i < 144 * 64) {
    rkP[i] = (i < NCC * DHH) ? (bf16)rpr_k[i] : (bf16)0.f;
  }
}

// ---- fused attention: LDS-shared K/V tiles (4 waves, 1 bh), QR prologue, 4-mode softmax ----
// Ks[32][64] / Vs[64][32] staged once per block per tile via global_load_lds with
// PRE-SWIZZLED SOURCE (LDS linear): K chunk ^= row&7 (reads 2-way), V chunk ^= d&3 (4-way).
// Per-wave arena (10240 B): [0,4736) QRs 16x148 | [4736,8832) SBand 16x128 f16 |
// [8832,10112) Pl 16x40 bf16 -> li/a0/a128 floats in epilogue; AW 16x168 overlays [0,5376).
__global__ __launch_bounds__(256, 3) void attn_mfma(
    const bf16* __restrict__ Qh, const bf16* __restrict__ Kh, const bf16* __restrict__ VhT,
    const bf16* __restrict__ rkP, const int* __restrict__ valid_lens,
    const bf16* __restrict__ rvT, bf16* __restrict__ Obh) {
  __shared__ __align__(16) bf16 Ks[32][64];
  __shared__ __align__(16) bf16 Vs[64][32];
  __shared__ __align__(16) char arena[4][10240];
  const int tid = threadIdx.x, lane = tid & 63, w = tid >> 6;
  const int l15 = lane & 15, l4 = lane >> 4;
  const int b = blockIdx.z, h = blockIdx.y, bh = b * HH + h;
  const int q0 = blockIdx.x * 64 + w * 16;
  const int vlen = valid_lens[b];
  const float mval = (vlen == 0) ? 0.f : -30000.f;
  char* base = arena[w];
  bf16* QRs = (bf16*)base;                      // [16][148]
  _Float16* SBand = (_Float16*)(base + 4736);   // [16][128]
  bf16* Pl = (bf16*)(base + 8832);              // [16][40]

  const bf16* Qbase = Qh + ((size_t)bh * SS + q0) * DHH;
  bf16x8 qa0 = *(const bf16x8*)(Qbase + (size_t)l15 * DHH + l4 * 8);
  bf16x8 qa1 = *(const bf16x8*)(Qbase + (size_t)l15 * DHH + 32 + l4 * 8);
  const bf16* Kbase = Kh + (size_t)bh * SS * DHH;
  const bf16* Vbase = VhT + (size_t)bh * DHH * SS;
  f32x4 z = {0.f, 0.f, 0.f, 0.f};

  // ---- QR prologue: QRs[q][c] = Q[q]·rpr_k[c] via 9x2 MFMA on pre-packed bf16 rkP ----
#pragma unroll
  for (int ni = 0; ni < 9; ni++) {
    const bf16* rp = rkP + (size_t)(ni * 16 + l15) * DHH + l4 * 8;
    bf16x8 b0 = *(const bf16x8*)(rp);
    bf16x8 b1 = *(const bf16x8*)(rp + 32);
    f32x4 acc = __builtin_amdgcn_mfma_f32_16x16x32_bf16(qa0, b0, z, 0, 0, 0);
    acc = __builtin_amdgcn_mfma_f32_16x16x32_bf16(qa1, b1, acc, 0, 0, 0);
#pragma unroll
    for (int r = 0; r < 4; r++)
      QRs[(l4 * 4 + r) * QRSTR + ni * 16 + l15] = (bf16)acc[r];
  }
  {
    _Float16 ninf = (_Float16)(-65504.f);
    for (int i = lane; i < 16 * 128; i += 64) SBand[i] = ninf;
  }

  float biasLo[4], biasHi[4];
#pragma unroll
  for (int r = 0; r < 4; r++) {
    biasLo[r] = (float)QRs[(l4 * 4 + r) * QRSTR + 0];
    biasHi[r] = (float)QRs[(l4 * 4 + r) * QRSTR + 128];
  }

  float l_lane[4], slo[4], shi[4];
#pragma unroll
  for (int r = 0; r < 4; r++) { l_lane[r] = 0.f; slo[r] = 0.f; shi[r] = 0.f; }
  f32x4 acco[4];
#pragma unroll
  for (int i = 0; i < 4; i++) acco[i] = z;

  // swizzled LDS read offsets (elems)
  const int ksw0 = (l4 ^ (l15 & 7)) * 8;
  const int ksw1 = ((l4 + 4) ^ (l15 & 7)) * 8;
  const int vsw  = (l4 ^ (l15 & 3)) * 8;
  // staging constants (source pre-swizzle, LDS linear)
  const int krow = w * 8 + (lane >> 3);
  const int kch  = ((lane & 7) ^ (krow & 7)) * 8;
  const int vd   = w * 16 + (lane >> 2);
  const int vch  = ((lane & 3) ^ (vd & 3)) * 8;

  // bounds: tail tiles [kfb, kte); band [bs, be) for this wave's q0
  const int kfb = (vlen > 0) ? (vlen & ~31) : 0;
  const int kte = (vlen > 0) ? ((vlen + 31) & ~31) : SS;
  int bs = q0 - 94; bs = (bs < 0) ? 0 : ((bs + 31) & ~31);
  int be = (q0 + 110) & ~31; if (be > SS) be = SS;

  for (int ks = 0; ks < kte; ks += 32) {
    gload_lds16(Kbase + (size_t)(ks + krow) * DHH + kch, &Ks[w * 8][0]);
    gload_lds16(Vbase + (size_t)vd * SS + ks + vch, &Vs[w * 16][0]);
    __syncthreads();
    bf16x8 kf00 = *(const bf16x8*)&Ks[l15][ksw0];
    bf16x8 kf01 = *(const bf16x8*)&Ks[l15][ksw1];
    bf16x8 kf10 = *(const bf16x8*)&Ks[16 + l15][ksw0];
    bf16x8 kf11 = *(const bf16x8*)&Ks[16 + l15][ksw1];
    f32x4 a0 = __builtin_amdgcn_mfma_f32_16x16x32_bf16(qa0, kf00, z, 0, 0, 0);
    a0 = __builtin_amdgcn_mfma_f32_16x16x32_bf16(qa1, kf01, a0, 0, 0, 0);
    f32x4 a1 = __builtin_amdgcn_mfma_f32_16x16x32_bf16(qa0, kf10, z, 0, 0, 0);
    a1 = __builtin_amdgcn_mfma_f32_16x16x32_bf16(qa1, kf11, a1, 0, 0, 0);

    if (ks >= kfb) {
      // masked tail (<=1 tile for vlen>0; all tiles for vlen==0)
      const int rel = ks - q0;
      const int mode = (rel <= -95) ? 0 : (rel >= 79) ? 1 : 2;
#pragma unroll
      for (int sub = 0; sub < 2; sub++) {
        const f32x4 a = sub ? a1 : a0;
        const int kg = ks + sub * 16 + l15;
        const bool msk = (kg >= vlen);
        if (mode == 0) {
#pragma unroll
          for (int r = 0; r < 4; r++) {
            float s = msk ? mval : (a[r] + biasLo[r]);
            float p = __expf(s - M0F);
            l_lane[r] += p; slo[r] += p;
            Pl[(l4 * 4 + r) * 40 + sub * 16 + l15] = (bf16)p;
          }
        } else if (mode == 1) {
#pragma unroll
          for (int r = 0; r < 4; r++) {
            float s = msk ? mval : (a[r] + biasHi[r]);
            float p = __expf(s - M0F);
            l_lane[r] += p; shi[r] += p;
            Pl[(l4 * 4 + r) * 40 + sub * 16 + l15] = (bf16)p;
          }
        } else {
#pragma unroll
          for (int r = 0; r < 4; r++) {
            const int qloc = l4 * 4 + r;
            int dlt = kg - q0 - qloc;
            int c = (dlt < -NCLIP ? -NCLIP : (dlt > NCLIP ? NCLIP : dlt)) + NCLIP;
            float s = a[r] + (float)QRs[qloc * QRSTR + c];
            if (msk) s = mval;
            if (dlt > -64 && dlt < 64) SBand[qloc * 128 + dlt + 63] = (_Float16)s;
            float p = __expf(s - M0F);
            l_lane[r] += p;
            slo[r] += (dlt <= -64) ? p : 0.f;
            shi[r] += (dlt >= 64) ? p : 0.f;
            Pl[qloc * 40 + sub * 16 + l15] = (bf16)p;
          }
        }
      }
    } else if (ks < bs) {
      // lo tiles (all dlt <= -64, unmasked)
#pragma unroll
      for (int sub = 0; sub < 2; sub++) {
        const f32x4 a = sub ? a1 : a0;
#pragma unroll
        for (int r = 0; r < 4; r++) {
          float p = __expf(a[r] + biasLo[r] - M0F);
          l_lane[r] += p; slo[r] += p;
          Pl[(l4 * 4 + r) * 40 + sub * 16 + l15] = (bf16)p;
        }
      }
    } else if (ks < be) {
      // band tiles (unmasked, full body)
#pragma unroll
      for (int sub = 0; sub < 2; sub++) {
        const f32x4 a = sub ? a1 : a0;
        const int kg = ks + sub * 16 + l15;
#pragma unroll
        for (int r = 0; r < 4; r++) {
          const int qloc = l4 * 4 + r;
          int dlt = kg - q0 - qloc;
          int c = (dlt < -NCLIP ? -NCLIP : (dlt > NCLIP ? NCLIP : dlt)) + NCLIP;
          float s = a[r] + (float)QRs[qloc * QRSTR + c];
          if (dlt > -64 && dlt < 64) SBand[qloc * 128 + dlt + 63] = (_Float16)s;
          float p = __expf(s - M0F);
          l_lane[r] += p;
          slo[r] += (dlt <= -64) ? p : 0.f;
          shi[r] += (dlt >= 64) ? p : 0.f;
          Pl[qloc * 40 + sub * 16 + l15] = (bf16)p;
        }
      }
    } else {
      // hi tiles (all dlt >= 64, unmasked)
#pragma unroll
      for (int sub = 0; sub < 2; sub++) {
        const f32x4 a = sub ? a1 : a0;
#pragma unroll
        for (int r = 0; r < 4; r++) {
          float p = __expf(a[r] + biasHi[r] - M0F);
          l_lane[r] += p; shi[r] += p;
          Pl[(l4 * 4 + r) * 40 + sub * 16 + l15] = (bf16)p;
        }
      }
    }

    bf16x8 pa = *(const bf16x8*)&Pl[l15 * 40 + l4 * 8];
    acco[0] = __builtin_amdgcn_mfma_f32_16x16x32_bf16(pa, *(const bf16x8*)&Vs[l15][vsw], acco[0], 0, 0, 0);
    acco[1] = __builtin_amdgcn_mfma_f32_16x16x32_bf16(pa, *(const bf16x8*)&Vs[16 + l15][vsw], acco[1], 0, 0, 0);
    acco[2] = __builtin_amdgcn_mfma_f32_16x16x32_bf16(pa, *(const bf16x8*)&Vs[32 + l15][vsw], acco[2], 0, 0, 0);
    acco[3] = __builtin_amdgcn_mfma_f32_16x16x32_bf16(pa, *(const bf16x8*)&Vs[48 + l15][vsw], acco[3], 0, 0, 0);
    __syncthreads();
  }

  // ---- epilogue step 1: reduce l/slo/shi; stash li, aw0, aw128 ----
  float* li_s   = (float*)(base + 8832);
  float* a0_s   = (float*)(base + 8896);
  float* a128_s = (float*)(base + 8960);
  float li_r[4];
#pragma unroll
  for (int r = 0; r < 4; r++) {
    const int qloc = l4 * 4 + r;
    float lt = l_lane[r], so = slo[r], sh = shi[r];
    lt += __shfl_xor(lt, 1, 64); so += __shfl_xor(so, 1, 64); sh += __shfl_xor(sh, 1, 64);
    lt += __shfl_xor(lt, 2, 64); so += __shfl_xor(so, 2, 64); sh += __shfl_xor(sh, 2, 64);
    lt += __shfl_xor(lt, 4, 64); so += __shfl_xor(so, 4, 64); sh += __shfl_xor(sh, 4, 64);
    lt += __shfl_xor(lt, 8, 64); so += __shfl_xor(so, 8, 64); sh += __shfl_xor(sh, 8, 64);
    float li = 1.f / lt;
    li_r[r] = li;
    if (l15 == 0) { li_s[qloc] = li; a0_s[qloc] = so * li; a128_s[qloc] = sh * li; }
  }
  // ---- step 2: materialize AW 16x168 bf16 at arena[0] ----
  bf16* AWs = (bf16*)base;
  for (int row = 0; row < 16; row++) {
    float li = li_s[row], a0 = a0_s[row], a128 = a128_s[row];
#pragma unroll
    for (int j = 0; j < 3; j++) {
      int c = lane + 64 * j;
      if (c < 160) {
        float val;
        if (c == 0) val = a0;
        else if (c == 128) val = a128;
        else if (c < 128) val = __expf((float)SBand[row * 128 + c - 1] - M0F) * li;
        else val = 0.f;
        AWs[row * 168 + c] = (bf16)val;
      }
    }
  }
  // ---- step 3: acc2 = AW @ rpr_v ----
  f32x4 acc2[4];
#pragma unroll
  for (int i = 0; i < 4; i++) acc2[i] = z;
#pragma unroll
  for (int kk = 0; kk < 5; kk++) {
    bf16x8 af = *(const bf16x8*)&AWs[l15 * 168 + kk * 32 + l4 * 8];
#pragma unroll
    for (int ni = 0; ni < 4; ni++) {
      bf16x8 bv = *(const bf16x8*)(rvT + (size_t)(ni * 16 + l15) * NCP + kk * 32 + l4 * 8);
      acc2[ni] = __builtin_amdgcn_mfma_f32_16x16x32_bf16(af, bv, acc2[ni], 0, 0, 0);
    }
  }
  // ---- step 4: write Obh bf16 ----
#pragma unroll
  for (int ni = 0; ni < 4; ni++)
#pragma unroll
    for (int r = 0; r < 4; r++) {
      int qg = q0 + l4 * 4 + r;
      Obh[((size_t)b * SS + qg) * DD + h * DHH + ni * 16 + l15] =
          (bf16)(acco[ni][r] * li_r[r] + acc2[ni][r]);
    }
}

extern "C" void kernel_launch(void* const* d_in, const int* in_sizes, int n_in,
                              void* d_out, int out_size, void* d_ws, size_t ws_size,
                              hipStream_t stream) {
  (void)in_sizes; (void)n_in; (void)out_size; (void)ws_size;
  const float* queries = (const float*)d_in[0];
  const float* keys    = (const float*)d_in[1];
  const float* values  = (const float*)d_in[2];
  const int*   vlens   = (const int*)d_in[3];
  const float* Wq = (const float*)d_in[4];
  const float* Wk = (const float*)d_in[5];
  const float* Wv = (const float*)d_in[6];
  const float* Wo = (const float*)d_in[7];
  const float* rpr_k = (const float*)d_in[8];
  const float* rpr_v = (const float*)d_in[9];

  char* ws = (char*)d_ws;
  const size_t MB = 1024 * 1024;
  bf16* Wtq  = (bf16*)(ws + 0 * MB);
  bf16* Wtk  = (bf16*)(ws + 2 * MB);
  bf16* Wtv  = (bf16*)(ws + 4 * MB);
  bf16* Wto  = (bf16*)(ws + 6 * MB);
  bf16* Qh   = (bf16*)(ws + 8 * MB);    // head-split, scaled 0.125
  bf16* Kh   = (bf16*)(ws + 16 * MB);
  bf16* Vh   = (bf16*)(ws + 24 * MB);
  bf16* VhT  = (bf16*)(ws + 32 * MB);
  bf16* Qb   = (bf16*)(ws + 40 * MB);
  bf16* Kb   = (bf16*)(ws + 48 * MB);
  bf16* Vb   = (bf16*)(ws + 56 * MB);
  bf16* Obh  = (bf16*)(ws + 64 * MB);   // 8 MB
  bf16* rvT  = (bf16*)(ws + 72 * MB);   // 20 KB
  bf16* rkP  = (bf16*)(ws + 73 * MB);   // 18 KB

  TpArgs tp; tp.w[0] = Wq; tp.w[1] = Wk; tp.w[2] = Wv; tp.w[3] = Wo;
  tp.wt[0] = Wtq; tp.wt[1] = Wtk; tp.wt[2] = Wtv; tp.wt[3] = Wto;
  transpose_pack_w<<<dim3(32, 32, 4), dim3(32, 8), 0, stream>>>(tp);

  CvtArgs cv; cv.in[0] = queries; cv.in[1] = keys; cv.in[2] = values;
  cv.out[0] = Qb; cv.out[1] = Kb; cv.out[2] = Vb;
  cv.skip[0] = 0; cv.skip[1] = 1; cv.skip[2] = 1;
  f32_to_bf16_3<<<dim3(2048, 1, 3), 256, 0, stream>>>(cv, vlens);

  GemmArgs gp;
  gp.a[0] = Qb; gp.a[1] = Kb; gp.a[2] = Vb;
  gp.bt[0] = Wtq; gp.bt[1] = Wtk; gp.bt[2] = Wtv;
  gp.c[0] = (void*)Qh; gp.c[1] = (void*)Kh; gp.c[2] = (void*)Vh;
  gp.sc[0] = 0.125f; gp.sc[1] = 1.0f; gp.sc[2] = 1.0f;
  gp.skip[0] = 0; gp.skip[1] = 1; gp.skip[2] = 1;
  gemm128<true><<<dim3(8, 32, 3), 256, 0, stream>>>(gp, vlens);

  vh_transpose<<<dim3(16, 64), 256, 0, stream>>>(Vh, VhT, vlens);
  prep_tables<<<dim3(40), 256, 0, stream>>>(rpr_v, rpr_k, rvT, rkP);
  attn_mfma<<<dim3(16, HH, BB), 256, 0, stream>>>(Qh, Kh, VhT, rkP, vlens, rvT, Obh);
  gemm_final128<<<dim3(8, 32), 256, 0, stream>>>(Obh, Wto, (float*)d_out);
}

// Round 17
// 114.898 us; speedup vs baseline: 1.0783x; 1.0650x over previous
//
#include <hip/hip_runtime.h>
#include <stdint.h>
#include <math.h>

#define BB 4
#define SS 1024
#define DD 1024
#define HH 16
#define DHH 64
#define NCLIP 64
#define NCC 129   // 2*CLIP+1
#define NCP 160   // padded bucket count
#define QRSTR 148 // QR row stride in LDS (bf16)
#define M0F 20.0f // fixed softmax max

typedef __bf16 bf16;
typedef __bf16 bf16x8 __attribute__((ext_vector_type(8)));
typedef float f32x4 __attribute__((ext_vector_type(4)));

__device__ __forceinline__ void gload_lds16(const void* g, void* l) {
  __builtin_amdgcn_global_load_lds((const __attribute__((address_space(1))) void*)g,
                                   (__attribute__((address_space(3))) void*)l, 16, 0, 0);
}

// ---------------- batched transpose + pack W: fp32 [K][N] -> bf16 [N][K] ----------------
struct TpArgs { const float* w[4]; bf16* wt[4]; };
__global__ __launch_bounds__(256) void transpose_pack_w(TpArgs args) {
  const float* __restrict__ W = args.w[blockIdx.z];
  bf16* __restrict__ Wt = args.wt[blockIdx.z];
  __shared__ float tile[32][33];
  int tx = threadIdx.x, ty = threadIdx.y;
  int n0 = blockIdx.x * 32, k0 = blockIdx.y * 32;
#pragma unroll
  for (int i = 0; i < 4; i++)
    tile[ty + i * 8][tx] = W[(size_t)(k0 + ty + i * 8) * DD + n0 + tx];
  __syncthreads();
#pragma unroll
  for (int i = 0; i < 4; i++)
    Wt[(size_t)(n0 + ty + i * 8) * DD + k0 + tx] = (bf16)tile[tx][ty + i * 8];
}

// ---------------- batched fp32 -> bf16 convert (8 elems/thread, vlen skip) ----------------
struct CvtArgs { const float* in[3]; bf16* out[3]; int skip[3]; };
__global__ __launch_bounds__(256) void f32_to_bf16_3(CvtArgs args, const int* __restrict__ vlens) {
  const int z = blockIdx.z;
  if (args.skip[z]) {
    int row0 = (blockIdx.x * 2) & 1023;
    int b = (blockIdx.x * 2) >> 10;
    int vl = vlens[b];
    if (vl > 0 && row0 >= vl) return;
  }
  const float* __restrict__ in = args.in[z];
  bf16* __restrict__ out = args.out[z];
  size_t i = ((size_t)blockIdx.x * 256 + threadIdx.x) * 8;
  f32x4 v0 = *(const f32x4*)(in + i);
  f32x4 v1 = *(const f32x4*)(in + i + 4);
  bf16x8 o;
#pragma unroll
  for (int j = 0; j < 4; j++) { o[j] = (bf16)v0[j]; o[j + 4] = (bf16)v1[j]; }
  *(bf16x8*)(out + i) = o;
}

// ---------------- 128x128 bf16 GEMM (m97-style), gload_lds staging, BK=32 ----------------
struct GemmArgs { const bf16* a[3]; const bf16* bt[3]; void* c[3]; float sc[3]; int skip[3]; };
template <bool SPLIT>
__global__ __launch_bounds__(256) void gemm128(GemmArgs args, const int* __restrict__ vlens) {
  const int z = blockIdx.z;
  const int m0 = blockIdx.y * 128, n0 = blockIdx.x * 128;
  if (args.skip[z]) {
    int vl = vlens[m0 >> 10];
    if (vl > 0 && (m0 & 1023) >= vl) return;
  }
  const bf16* __restrict__ A  = args.a[z];
  const bf16* __restrict__ Bt = args.bt[z];
  void* __restrict__ Cv = args.c[z];
  const float scale = args.sc[z];
  __shared__ __align__(16) bf16 As[128][32];
  __shared__ __align__(16) bf16 Bs[128][32];
  const int tid = threadIdx.x, lane = tid & 63, wv = tid >> 6;
  const int wr = wv >> 1, wc = wv & 1;
  const int l15 = lane & 15, l4 = lane >> 4;
  const int srow = lane >> 2, scol = (lane & 3) * 8;
  f32x4 z4 = {0.f, 0.f, 0.f, 0.f};
  f32x4 acc[4][4];
#pragma unroll
  for (int i = 0; i < 4; i++)
#pragma unroll
    for (int j = 0; j < 4; j++) acc[i][j] = z4;

  for (int k0 = 0; k0 < DD; k0 += 32) {
    gload_lds16(A  + (size_t)(m0 + wv * 16 + srow) * DD + k0 + scol,      &As[wv * 16][0]);
    gload_lds16(A  + (size_t)(m0 + 64 + wv * 16 + srow) * DD + k0 + scol, &As[64 + wv * 16][0]);
    gload_lds16(Bt + (size_t)(n0 + wv * 16 + srow) * DD + k0 + scol,      &Bs[wv * 16][0]);
    gload_lds16(Bt + (size_t)(n0 + 64 + wv * 16 + srow) * DD + k0 + scol, &Bs[64 + wv * 16][0]);
    __syncthreads();
    bf16x8 af[4], bfv[4];
#pragma unroll
    for (int i = 0; i < 4; i++) {
      af[i]  = *(const bf16x8*)&As[wr * 64 + i * 16 + l15][l4 * 8];
      bfv[i] = *(const bf16x8*)&Bs[wc * 64 + i * 16 + l15][l4 * 8];
    }
#pragma unroll
    for (int mi = 0; mi < 4; mi++)
#pragma unroll
      for (int ni = 0; ni < 4; ni++)
        acc[mi][ni] = __builtin_amdgcn_mfma_f32_16x16x32_bf16(af[mi], bfv[ni], acc[mi][ni], 0, 0, 0);
    __syncthreads();
  }
#pragma unroll
  for (int mi = 0; mi < 4; mi++)
#pragma unroll
    for (int ni = 0; ni < 4; ni++)
#pragma unroll
      for (int r = 0; r < 4; r++) {
        int m = m0 + wr * 64 + mi * 16 + l4 * 4 + r;
        int n = n0 + wc * 64 + ni * 16 + l15;
        float val = acc[mi][ni][r] * scale;
        if (SPLIT) {
          ((bf16*)Cv)[((((size_t)(m >> 10) * HH + (n >> 6)) * SS) + (m & 1023)) * DHH + (n & 63)] =
              (bf16)val;
        } else {
          ((float*)Cv)[(size_t)m * DD + n] = val;
        }
      }
}

// ---- final projection: 64x128 gemm (512 blocks, 2/CU), chunked-XCD linear remap ----
__global__ __launch_bounds__(256) void gemm_bf16_final(const bf16* __restrict__ A,
                                                       const bf16* __restrict__ Bt,
                                                       float* __restrict__ C) {
  // linear block id i -> XCD i%8; remap so XCD k owns logical [64k, 64k+64):
  // 8 contiguous M-panels x all 8 N-panels (A fetched once per panel, B 8x).
  const int ilin = (int)blockIdx.y * 8 + (int)blockIdx.x;
  const int logical = (ilin & 7) * 64 + (ilin >> 3);
  const int m0 = (logical >> 3) * 64, n0 = (logical & 7) * 128;
  __shared__ __align__(16) bf16 As[64][32];
  __shared__ __align__(16) bf16 Bs[128][32];
  const int tid = threadIdx.x, lane = tid & 63, wv = tid >> 6;
  const int l15 = lane & 15, l4 = lane >> 4;
  const int srow = lane >> 2, scol = (lane & 3) * 8;
  f32x4 z4 = {0.f, 0.f, 0.f, 0.f};
  f32x4 acc[4][2];
#pragma unroll
  for (int i = 0; i < 4; i++) { acc[i][0] = z4; acc[i][1] = z4; }

  for (int k0 = 0; k0 < DD; k0 += 32) {
    gload_lds16(A + (size_t)(m0 + wv * 16 + srow) * DD + k0 + scol, &As[wv * 16][0]);
    gload_lds16(Bt + (size_t)(n0 + wv * 32 + srow) * DD + k0 + scol, &Bs[wv * 32][0]);
    gload_lds16(Bt + (size_t)(n0 + wv * 32 + 16 + srow) * DD + k0 + scol, &Bs[wv * 32 + 16][0]);
    __syncthreads();
    bf16x8 af[4], bfv[2];
#pragma unroll
    for (int i = 0; i < 4; i++) af[i] = *(const bf16x8*)&As[i * 16 + l15][l4 * 8];
#pragma unroll
    for (int i = 0; i < 2; i++) bfv[i] = *(const bf16x8*)&Bs[wv * 32 + i * 16 + l15][l4 * 8];
#pragma unroll
    for (int mi = 0; mi < 4; mi++)
#pragma unroll
      for (int ni = 0; ni < 2; ni++)
        acc[mi][ni] = __builtin_amdgcn_mfma_f32_16x16x32_bf16(af[mi], bfv[ni], acc[mi][ni], 0, 0, 0);
    __syncthreads();
  }
#pragma unroll
  for (int mi = 0; mi < 4; mi++)
#pragma unroll
    for (int ni = 0; ni < 2; ni++)
#pragma unroll
      for (int r = 0; r < 4; r++) {
        int m = m0 + mi * 16 + l4 * 4 + r;
        int n = n0 + wv * 32 + ni * 16 + l15;
        C[(size_t)m * DD + n] = acc[mi][ni][r];
      }
}

// ---------------- Vh [bh][s][d] -> VhT [bh][d][s]  (vlen skip) ----------------
__global__ __launch_bounds__(256) void vh_transpose(const bf16* __restrict__ Vh,
                                                    bf16* __restrict__ VhT,
                                                    const int* __restrict__ vlens) {
  __shared__ bf16 til[64][65];
  int bh = blockIdx.y;
  int s0 = blockIdx.x * 64;
  int vl = vlens[bh >> 4];
  if (vl > 0 && s0 >= vl + 32) return;
  const bf16* src = Vh + (size_t)bh * SS * DHH + (size_t)s0 * DHH;
  for (int i = threadIdx.x; i < 64 * 64; i += 256) {
    int r = i >> 6, cc = i & 63;
    til[r][cc] = src[(size_t)r * DHH + cc];
  }
  __syncthreads();
  bf16* dst = VhT + (size_t)bh * DHH * SS + s0;
  for (int i = threadIdx.x; i < 64 * 64; i += 256) {
    int d = i >> 6, cc = i & 63;
    dst[(size_t)d * SS + cc] = til[cc][d];
  }
}

// ------- prep tables: rvT bf16 [64][160] (rpr_v^T, padded) + rkP bf16 [144][64] -------
__global__ void prep_tables(const float* __restrict__ rpr_v, const float* __restrict__ rpr_k,
                            bf16* __restrict__ rvT, bf16* __restrict__ rkP) {
  int i = blockIdx.x * 256 + threadIdx.x;
  if (i < DHH * NCP) {
    int d = i / NCP, c = i - d * NCP;
    rvT[i] = (c < NCC) ? (bf16)rpr_v[(size_t)c * DHH + d] : (bf16)0.f;
  }
  if (i < 144 * 64) {
    rkP[i] = (i < NCC * DHH) ? (bf16)rpr_k[i] : (bf16)0.f;
  }
}

// ---- fused attention: LDS-shared K/V tiles (4 waves, 1 bh), QR prologue, 4-mode softmax ----
// Ks[32][64] / Vs[64][32] staged once per block per tile via global_load_lds with
// PRE-SWIZZLED SOURCE (LDS linear): K chunk ^= row&7 (reads 2-way), V chunk ^= d&3 (4-way).
// Per-wave arena (10240 B): [0,4736) QRs 16x148 | [4736,8832) SBand 16x128 f16 |
// [8832,10112) Pl 16x40 bf16 -> li/a0/a128 floats in epilogue; AW 16x168 overlays [0,5376).
__global__ __launch_bounds__(256, 3) void attn_mfma(
    const bf16* __restrict__ Qh, const bf16* __restrict__ Kh, const bf16* __restrict__ VhT,
    const bf16* __restrict__ rkP, const int* __restrict__ valid_lens,
    const bf16* __restrict__ rvT, bf16* __restrict__ Obh) {
  __shared__ __align__(16) bf16 Ks[32][64];
  __shared__ __align__(16) bf16 Vs[64][32];
  __shared__ __align__(16) char arena[4][10240];
  const int tid = threadIdx.x, lane = tid & 63, w = tid >> 6;
  const int l15 = lane & 15, l4 = lane >> 4;
  const int b = blockIdx.z, h = blockIdx.y, bh = b * HH + h;
  const int q0 = blockIdx.x * 64 + w * 16;
  const int vlen = valid_lens[b];
  const float mval = (vlen == 0) ? 0.f : -30000.f;
  char* base = arena[w];
  bf16* QRs = (bf16*)base;                      // [16][148]
  _Float16* SBand = (_Float16*)(base + 4736);   // [16][128]
  bf16* Pl = (bf16*)(base + 8832);              // [16][40]

  const bf16* Qbase = Qh + ((size_t)bh * SS + q0) * DHH;
  bf16x8 qa0 = *(const bf16x8*)(Qbase + (size_t)l15 * DHH + l4 * 8);
  bf16x8 qa1 = *(const bf16x8*)(Qbase + (size_t)l15 * DHH + 32 + l4 * 8);
  const bf16* Kbase = Kh + (size_t)bh * SS * DHH;
  const bf16* Vbase = VhT + (size_t)bh * DHH * SS;
  f32x4 z = {0.f, 0.f, 0.f, 0.f};

  // ---- QR prologue: QRs[q][c] = Q[q]·rpr_k[c] via 9x2 MFMA on pre-packed bf16 rkP ----
#pragma unroll
  for (int ni = 0; ni < 9; ni++) {
    const bf16* rp = rkP + (size_t)(ni * 16 + l15) * DHH + l4 * 8;
    bf16x8 b0 = *(const bf16x8*)(rp);
    bf16x8 b1 = *(const bf16x8*)(rp + 32);
    f32x4 acc = __builtin_amdgcn_mfma_f32_16x16x32_bf16(qa0, b0, z, 0, 0, 0);
    acc = __builtin_amdgcn_mfma_f32_16x16x32_bf16(qa1, b1, acc, 0, 0, 0);
#pragma unroll
    for (int r = 0; r < 4; r++)
      QRs[(l4 * 4 + r) * QRSTR + ni * 16 + l15] = (bf16)acc[r];
  }
  {
    _Float16 ninf = (_Float16)(-65504.f);
    for (int i = lane; i < 16 * 128; i += 64) SBand[i] = ninf;
  }

  float biasLo[4], biasHi[4];
#pragma unroll
  for (int r = 0; r < 4; r++) {
    biasLo[r] = (float)QRs[(l4 * 4 + r) * QRSTR + 0];
    biasHi[r] = (float)QRs[(l4 * 4 + r) * QRSTR + 128];
  }

  float l_lane[4], slo[4], shi[4];
#pragma unroll
  for (int r = 0; r < 4; r++) { l_lane[r] = 0.f; slo[r] = 0.f; shi[r] = 0.f; }
  f32x4 acco[4];
#pragma unroll
  for (int i = 0; i < 4; i++) acco[i] = z;

  // swizzled LDS read offsets (elems)
  const int ksw0 = (l4 ^ (l15 & 7)) * 8;
  const int ksw1 = ((l4 + 4) ^ (l15 & 7)) * 8;
  const int vsw  = (l4 ^ (l15 & 3)) * 8;
  // staging constants (source pre-swizzle, LDS linear)
  const int krow = w * 8 + (lane >> 3);
  const int kch  = ((lane & 7) ^ (krow & 7)) * 8;
  const int vd   = w * 16 + (lane >> 2);
  const int vch  = ((lane & 3) ^ (vd & 3)) * 8;

  // bounds: tail tiles [kfb, kte); band [bs, be) for this wave's q0
  const int kfb = (vlen > 0) ? (vlen & ~31) : 0;
  const int kte = (vlen > 0) ? ((vlen + 31) & ~31) : SS;
  int bs = q0 - 94; bs = (bs < 0) ? 0 : ((bs + 31) & ~31);
  int be = (q0 + 110) & ~31; if (be > SS) be = SS;

  for (int ks = 0; ks < kte; ks += 32) {
    gload_lds16(Kbase + (size_t)(ks + krow) * DHH + kch, &Ks[w * 8][0]);
    gload_lds16(Vbase + (size_t)vd * SS + ks + vch, &Vs[w * 16][0]);
    __syncthreads();
    bf16x8 kf00 = *(const bf16x8*)&Ks[l15][ksw0];
    bf16x8 kf01 = *(const bf16x8*)&Ks[l15][ksw1];
    bf16x8 kf10 = *(const bf16x8*)&Ks[16 + l15][ksw0];
    bf16x8 kf11 = *(const bf16x8*)&Ks[16 + l15][ksw1];
    f32x4 a0 = __builtin_amdgcn_mfma_f32_16x16x32_bf16(qa0, kf00, z, 0, 0, 0);
    a0 = __builtin_amdgcn_mfma_f32_16x16x32_bf16(qa1, kf01, a0, 0, 0, 0);
    f32x4 a1 = __builtin_amdgcn_mfma_f32_16x16x32_bf16(qa0, kf10, z, 0, 0, 0);
    a1 = __builtin_amdgcn_mfma_f32_16x16x32_bf16(qa1, kf11, a1, 0, 0, 0);

    if (ks >= kfb) {
      // masked tail (<=1 tile for vlen>0; all tiles for vlen==0)
      const int rel = ks - q0;
      const int mode = (rel <= -95) ? 0 : (rel >= 79) ? 1 : 2;
#pragma unroll
      for (int sub = 0; sub < 2; sub++) {
        const f32x4 a = sub ? a1 : a0;
        const int kg = ks + sub * 16 + l15;
        const bool msk = (kg >= vlen);
        if (mode == 0) {
#pragma unroll
          for (int r = 0; r < 4; r++) {
            float s = msk ? mval : (a[r] + biasLo[r]);
            float p = __expf(s - M0F);
            l_lane[r] += p; slo[r] += p;
            Pl[(l4 * 4 + r) * 40 + sub * 16 + l15] = (bf16)p;
          }
        } else if (mode == 1) {
#pragma unroll
          for (int r = 0; r < 4; r++) {
            float s = msk ? mval : (a[r] + biasHi[r]);
            float p = __expf(s - M0F);
            l_lane[r] += p; shi[r] += p;
            Pl[(l4 * 4 + r) * 40 + sub * 16 + l15] = (bf16)p;
          }
        } else {
#pragma unroll
          for (int r = 0; r < 4; r++) {
            const int qloc = l4 * 4 + r;
            int dlt = kg - q0 - qloc;
            int c = (dlt < -NCLIP ? -NCLIP : (dlt > NCLIP ? NCLIP : dlt)) + NCLIP;
            float s = a[r] + (float)QRs[qloc * QRSTR + c];
            if (msk) s = mval;
            if (dlt > -64 && dlt < 64) SBand[qloc * 128 + dlt + 63] = (_Float16)s;
            float p = __expf(s - M0F);
            l_lane[r] += p;
            slo[r] += (dlt <= -64) ? p : 0.f;
            shi[r] += (dlt >= 64) ? p : 0.f;
            Pl[qloc * 40 + sub * 16 + l15] = (bf16)p;
          }
        }
      }
    } else if (ks < bs) {
      // lo tiles (all dlt <= -64, unmasked)
#pragma unroll
      for (int sub = 0; sub < 2; sub++) {
        const f32x4 a = sub ? a1 : a0;
#pragma unroll
        for (int r = 0; r < 4; r++) {
          float p = __expf(a[r] + biasLo[r] - M0F);
          l_lane[r] += p; slo[r] += p;
          Pl[(l4 * 4 + r) * 40 + sub * 16 + l15] = (bf16)p;
        }
      }
    } else if (ks < be) {
      // band tiles (unmasked, full body)
#pragma unroll
      for (int sub = 0; sub < 2; sub++) {
        const f32x4 a = sub ? a1 : a0;
        const int kg = ks + sub * 16 + l15;
#pragma unroll
        for (int r = 0; r < 4; r++) {
          const int qloc = l4 * 4 + r;
          int dlt = kg - q0 - qloc;
          int c = (dlt < -NCLIP ? -NCLIP : (dlt > NCLIP ? NCLIP : dlt)) + NCLIP;
          float s = a[r] + (float)QRs[qloc * QRSTR + c];
          if (dlt > -64 && dlt < 64) SBand[qloc * 128 + dlt + 63] = (_Float16)s;
          float p = __expf(s - M0F);
          l_lane[r] += p;
          slo[r] += (dlt <= -64) ? p : 0.f;
          shi[r] += (dlt >= 64) ? p : 0.f;
          Pl[qloc * 40 + sub * 16 + l15] = (bf16)p;
        }
      }
    } else {
      // hi tiles (all dlt >= 64, unmasked)
#pragma unroll
      for (int sub = 0; sub < 2; sub++) {
        const f32x4 a = sub ? a1 : a0;
#pragma unroll
        for (int r = 0; r < 4; r++) {
          float p = __expf(a[r] + biasHi[r] - M0F);
          l_lane[r] += p; shi[r] += p;
          Pl[(l4 * 4 + r) * 40 + sub * 16 + l15] = (bf16)p;
        }
      }
    }

    bf16x8 pa = *(const bf16x8*)&Pl[l15 * 40 + l4 * 8];
    acco[0] = __builtin_amdgcn_mfma_f32_16x16x32_bf16(pa, *(const bf16x8*)&Vs[l15][vsw], acco[0], 0, 0, 0);
    acco[1] = __builtin_amdgcn_mfma_f32_16x16x32_bf16(pa, *(const bf16x8*)&Vs[16 + l15][vsw], acco[1], 0, 0, 0);
    acco[2] = __builtin_amdgcn_mfma_f32_16x16x32_bf16(pa, *(const bf16x8*)&Vs[32 + l15][vsw], acco[2], 0, 0, 0);
    acco[3] = __builtin_amdgcn_mfma_f32_16x16x32_bf16(pa, *(const bf16x8*)&Vs[48 + l15][vsw], acco[3], 0, 0, 0);
    __syncthreads();
  }

  // ---- epilogue step 1: reduce l/slo/shi; stash li, aw0, aw128 ----
  float* li_s   = (float*)(base + 8832);
  float* a0_s   = (float*)(base + 8896);
  float* a128_s = (float*)(base + 8960);
  float li_r[4];
#pragma unroll
  for (int r = 0; r < 4; r++) {
    const int qloc = l4 * 4 + r;
    float lt = l_lane[r], so = slo[r], sh = shi[r];
    lt += __shfl_xor(lt, 1, 64); so += __shfl_xor(so, 1, 64); sh += __shfl_xor(sh, 1, 64);
    lt += __shfl_xor(lt, 2, 64); so += __shfl_xor(so, 2, 64); sh += __shfl_xor(sh, 2, 64);
    lt += __shfl_xor(lt, 4, 64); so += __shfl_xor(so, 4, 64); sh += __shfl_xor(sh, 4, 64);
    lt += __shfl_xor(lt, 8, 64); so += __shfl_xor(so, 8, 64); sh += __shfl_xor(sh, 8, 64);
    float li = 1.f / lt;
    li_r[r] = li;
    if (l15 == 0) { li_s[qloc] = li; a0_s[qloc] = so * li; a128_s[qloc] = sh * li; }
  }
  // ---- step 2: materialize AW 16x168 bf16 at arena[0] ----
  bf16* AWs = (bf16*)base;
  for (int row = 0; row < 16; row++) {
    float li = li_s[row], a0 = a0_s[row], a128 = a128_s[row];
#pragma unroll
    for (int j = 0; j < 3; j++) {
      int c = lane + 64 * j;
      if (c < 160) {
        float val;
        if (c == 0) val = a0;
        else if (c == 128) val = a128;
        else if (c < 128) val = __expf((float)SBand[row * 128 + c - 1] - M0F) * li;
        else val = 0.f;
        AWs[row * 168 + c] = (bf16)val;
      }
    }
  }
  // ---- step 3: acc2 = AW @ rpr_v ----
  f32x4 acc2[4];
#pragma unroll
  for (int i = 0; i < 4; i++) acc2[i] = z;
#pragma unroll
  for (int kk = 0; kk < 5; kk++) {
    bf16x8 af = *(const bf16x8*)&AWs[l15 * 168 + kk * 32 + l4 * 8];
#pragma unroll
    for (int ni = 0; ni < 4; ni++) {
      bf16x8 bv = *(const bf16x8*)(rvT + (size_t)(ni * 16 + l15) * NCP + kk * 32 + l4 * 8);
      acc2[ni] = __builtin_amdgcn_mfma_f32_16x16x32_bf16(af, bv, acc2[ni], 0, 0, 0);
    }
  }
  // ---- step 4: write Obh bf16 ----
#pragma unroll
  for (int ni = 0; ni < 4; ni++)
#pragma unroll
    for (int r = 0; r < 4; r++) {
      int qg = q0 + l4 * 4 + r;
      Obh[((size_t)b * SS + qg) * DD + h * DHH + ni * 16 + l15] =
          (bf16)(acco[ni][r] * li_r[r] + acc2[ni][r]);
    }
}

extern "C" void kernel_launch(void* const* d_in, const int* in_sizes, int n_in,
                              void* d_out, int out_size, void* d_ws, size_t ws_size,
                              hipStream_t stream) {
  (void)in_sizes; (void)n_in; (void)out_size; (void)ws_size;
  const float* queries = (const float*)d_in[0];
  const float* keys    = (const float*)d_in[1];
  const float* values  = (const float*)d_in[2];
  const int*   vlens   = (const int*)d_in[3];
  const float* Wq = (const float*)d_in[4];
  const float* Wk = (const float*)d_in[5];
  const float* Wv = (const float*)d_in[6];
  const float* Wo = (const float*)d_in[7];
  const float* rpr_k = (const float*)d_in[8];
  const float* rpr_v = (const float*)d_in[9];

  char* ws = (char*)d_ws;
  const size_t MB = 1024 * 1024;
  bf16* Wtq  = (bf16*)(ws + 0 * MB);
  bf16* Wtk  = (bf16*)(ws + 2 * MB);
  bf16* Wtv  = (bf16*)(ws + 4 * MB);
  bf16* Wto  = (bf16*)(ws + 6 * MB);
  bf16* Qh   = (bf16*)(ws + 8 * MB);    // head-split, scaled 0.125
  bf16* Kh   = (bf16*)(ws + 16 * MB);
  bf16* Vh   = (bf16*)(ws + 24 * MB);
  bf16* VhT  = (bf16*)(ws + 32 * MB);
  bf16* Qb   = (bf16*)(ws + 40 * MB);
  bf16* Kb   = (bf16*)(ws + 48 * MB);
  bf16* Vb   = (bf16*)(ws + 56 * MB);
  bf16* Obh  = (bf16*)(ws + 64 * MB);   // 8 MB
  bf16* rvT  = (bf16*)(ws + 72 * MB);   // 20 KB
  bf16* rkP  = (bf16*)(ws + 73 * MB);   // 18 KB

  TpArgs tp; tp.w[0] = Wq; tp.w[1] = Wk; tp.w[2] = Wv; tp.w[3] = Wo;
  tp.wt[0] = Wtq; tp.wt[1] = Wtk; tp.wt[2] = Wtv; tp.wt[3] = Wto;
  transpose_pack_w<<<dim3(32, 32, 4), dim3(32, 8), 0, stream>>>(tp);

  CvtArgs cv; cv.in[0] = queries; cv.in[1] = keys; cv.in[2] = values;
  cv.out[0] = Qb; cv.out[1] = Kb; cv.out[2] = Vb;
  cv.skip[0] = 0; cv.skip[1] = 1; cv.skip[2] = 1;
  f32_to_bf16_3<<<dim3(2048, 1, 3), 256, 0, stream>>>(cv, vlens);

  GemmArgs gp;
  gp.a[0] = Qb; gp.a[1] = Kb; gp.a[2] = Vb;
  gp.bt[0] = Wtq; gp.bt[1] = Wtk; gp.bt[2] = Wtv;
  gp.c[0] = (void*)Qh; gp.c[1] = (void*)Kh; gp.c[2] = (void*)Vh;
  gp.sc[0] = 0.125f; gp.sc[1] = 1.0f; gp.sc[2] = 1.0f;
  gp.skip[0] = 0; gp.skip[1] = 1; gp.skip[2] = 1;
  gemm128<true><<<dim3(8, 32, 3), 256, 0, stream>>>(gp, vlens);

  vh_transpose<<<dim3(16, 64), 256, 0, stream>>>(Vh, VhT, vlens);
  prep_tables<<<dim3(40), 256, 0, stream>>>(rpr_v, rpr_k, rvT, rkP);
  attn_mfma<<<dim3(16, HH, BB), 256, 0, stream>>>(Qh, Kh, VhT, rkP, vlens, rvT, Obh);
  gemm_bf16_final<<<dim3(8, 64), 256, 0, stream>>>(Obh, Wto, (float*)d_out);
}

// Round 18
// 113.030 us; speedup vs baseline: 1.0962x; 1.0165x over previous
//
#include <hip/hip_runtime.h>
#include <stdint.h>
#include <math.h>

#define BB 4
#define SS 1024
#define DD 1024
#define HH 16
#define DHH 64
#define NCLIP 64
#define NCC 129   // 2*CLIP+1
#define NCP 160   // padded bucket count
#define QRSTR 148 // QR row stride in LDS (bf16)
#define M0F 20.0f // fixed softmax max

typedef __bf16 bf16;
typedef __bf16 bf16x8 __attribute__((ext_vector_type(8)));
typedef float f32x4 __attribute__((ext_vector_type(4)));
typedef uint32_t u32x4 __attribute__((ext_vector_type(4)));

__device__ __forceinline__ void gload_lds16(const void* g, void* l) {
  __builtin_amdgcn_global_load_lds((const __attribute__((address_space(1))) void*)g,
                                   (__attribute__((address_space(3))) void*)l, 16, 0, 0);
}

// ---------------- batched transpose + pack W: fp32 [K][N] -> bf16 [N][K] ----------------
struct TpArgs { const float* w[4]; bf16* wt[4]; };
__global__ __launch_bounds__(256) void transpose_pack_w(TpArgs args) {
  const float* __restrict__ W = args.w[blockIdx.z];
  bf16* __restrict__ Wt = args.wt[blockIdx.z];
  __shared__ float tile[32][33];
  int tx = threadIdx.x, ty = threadIdx.y;
  int n0 = blockIdx.x * 32, k0 = blockIdx.y * 32;
#pragma unroll
  for (int i = 0; i < 4; i++)
    tile[ty + i * 8][tx] = W[(size_t)(k0 + ty + i * 8) * DD + n0 + tx];
  __syncthreads();
#pragma unroll
  for (int i = 0; i < 4; i++)
    Wt[(size_t)(n0 + ty + i * 8) * DD + k0 + tx] = (bf16)tile[tx][ty + i * 8];
}

// ---- batched fp32 -> bf16 convert (z=0..2, vlen skip) + table prep (z=3) ----
struct CvtArgs {
  const float* in[3]; bf16* out[3]; int skip[3];
  const float* rpr_v; const float* rpr_k; bf16* rvT; bf16* rkP;
};
__global__ __launch_bounds__(256) void f32_to_bf16_3(CvtArgs args, const int* __restrict__ vlens) {
  const int z = blockIdx.z;
  if (z == 3) {   // table prep: rvT [64][160] (rpr_v^T, padded) + rkP [144][64]
    if (blockIdx.x >= 40) return;
    int i = blockIdx.x * 256 + threadIdx.x;
    if (i < DHH * NCP) {
      int d = i / NCP, c = i - d * NCP;
      args.rvT[i] = (c < NCC) ? (bf16)args.rpr_v[(size_t)c * DHH + d] : (bf16)0.f;
    }
    if (i < 144 * 64) {
      args.rkP[i] = (i < NCC * DHH) ? (bf16)args.rpr_k[i] : (bf16)0.f;
    }
    return;
  }
  if (args.skip[z]) {
    int row0 = (blockIdx.x * 2) & 1023;
    int b = (blockIdx.x * 2) >> 10;
    int vl = vlens[b];
    if (vl > 0 && row0 >= vl) return;
  }
  const float* __restrict__ in = args.in[z];
  bf16* __restrict__ out = args.out[z];
  size_t i = ((size_t)blockIdx.x * 256 + threadIdx.x) * 8;
  f32x4 v0 = *(const f32x4*)(in + i);
  f32x4 v1 = *(const f32x4*)(in + i + 4);
  bf16x8 o;
#pragma unroll
  for (int j = 0; j < 4; j++) { o[j] = (bf16)v0[j]; o[j + 4] = (bf16)v1[j]; }
  *(bf16x8*)(out + i) = o;
}

// ---------------- 128x128 bf16 GEMM (m97-style), gload_lds staging, BK=32 ----------------
struct GemmArgs { const bf16* a[3]; const bf16* bt[3]; void* c[3]; float sc[3]; int skip[3]; };
template <bool SPLIT>
__global__ __launch_bounds__(256) void gemm128(GemmArgs args, const int* __restrict__ vlens) {
  const int z = blockIdx.z;
  const int m0 = blockIdx.y * 128, n0 = blockIdx.x * 128;
  if (args.skip[z]) {
    int vl = vlens[m0 >> 10];
    if (vl > 0 && (m0 & 1023) >= vl) return;
  }
  const bf16* __restrict__ A  = args.a[z];
  const bf16* __restrict__ Bt = args.bt[z];
  void* __restrict__ Cv = args.c[z];
  const float scale = args.sc[z];
  __shared__ __align__(16) bf16 As[128][32];
  __shared__ __align__(16) bf16 Bs[128][32];
  const int tid = threadIdx.x, lane = tid & 63, wv = tid >> 6;
  const int wr = wv >> 1, wc = wv & 1;
  const int l15 = lane & 15, l4 = lane >> 4;
  const int srow = lane >> 2, scol = (lane & 3) * 8;
  f32x4 z4 = {0.f, 0.f, 0.f, 0.f};
  f32x4 acc[4][4];
#pragma unroll
  for (int i = 0; i < 4; i++)
#pragma unroll
    for (int j = 0; j < 4; j++) acc[i][j] = z4;

  for (int k0 = 0; k0 < DD; k0 += 32) {
    gload_lds16(A  + (size_t)(m0 + wv * 16 + srow) * DD + k0 + scol,      &As[wv * 16][0]);
    gload_lds16(A  + (size_t)(m0 + 64 + wv * 16 + srow) * DD + k0 + scol, &As[64 + wv * 16][0]);
    gload_lds16(Bt + (size_t)(n0 + wv * 16 + srow) * DD + k0 + scol,      &Bs[wv * 16][0]);
    gload_lds16(Bt + (size_t)(n0 + 64 + wv * 16 + srow) * DD + k0 + scol, &Bs[64 + wv * 16][0]);
    __syncthreads();
    bf16x8 af[4], bfv[4];
#pragma unroll
    for (int i = 0; i < 4; i++) {
      af[i]  = *(const bf16x8*)&As[wr * 64 + i * 16 + l15][l4 * 8];
      bfv[i] = *(const bf16x8*)&Bs[wc * 64 + i * 16 + l15][l4 * 8];
    }
#pragma unroll
    for (int mi = 0; mi < 4; mi++)
#pragma unroll
      for (int ni = 0; ni < 4; ni++)
        acc[mi][ni] = __builtin_amdgcn_mfma_f32_16x16x32_bf16(af[mi], bfv[ni], acc[mi][ni], 0, 0, 0);
    __syncthreads();
  }
#pragma unroll
  for (int mi = 0; mi < 4; mi++)
#pragma unroll
    for (int ni = 0; ni < 4; ni++)
#pragma unroll
      for (int r = 0; r < 4; r++) {
        int m = m0 + wr * 64 + mi * 16 + l4 * 4 + r;
        int n = n0 + wc * 64 + ni * 16 + l15;
        float val = acc[mi][ni][r] * scale;
        if (SPLIT) {
          ((bf16*)Cv)[((((size_t)(m >> 10) * HH + (n >> 6)) * SS) + (m & 1023)) * DHH + (n & 63)] =
              (bf16)val;
        } else {
          ((float*)Cv)[(size_t)m * DD + n] = val;
        }
      }
}

// ---- final projection: 64x128 gemm (512 blocks, 2/CU), chunked-XCD linear remap ----
__global__ __launch_bounds__(256) void gemm_bf16_final(const bf16* __restrict__ A,
                                                       const bf16* __restrict__ Bt,
                                                       float* __restrict__ C) {
  const int ilin = (int)blockIdx.y * 8 + (int)blockIdx.x;
  const int logical = (ilin & 7) * 64 + (ilin >> 3);
  const int m0 = (logical >> 3) * 64, n0 = (logical & 7) * 128;
  __shared__ __align__(16) bf16 As[64][32];
  __shared__ __align__(16) bf16 Bs[128][32];
  const int tid = threadIdx.x, lane = tid & 63, wv = tid >> 6;
  const int l15 = lane & 15, l4 = lane >> 4;
  const int srow = lane >> 2, scol = (lane & 3) * 8;
  f32x4 z4 = {0.f, 0.f, 0.f, 0.f};
  f32x4 acc[4][2];
#pragma unroll
  for (int i = 0; i < 4; i++) { acc[i][0] = z4; acc[i][1] = z4; }

  for (int k0 = 0; k0 < DD; k0 += 32) {
    gload_lds16(A + (size_t)(m0 + wv * 16 + srow) * DD + k0 + scol, &As[wv * 16][0]);
    gload_lds16(Bt + (size_t)(n0 + wv * 32 + srow) * DD + k0 + scol, &Bs[wv * 32][0]);
    gload_lds16(Bt + (size_t)(n0 + wv * 32 + 16 + srow) * DD + k0 + scol, &Bs[wv * 32 + 16][0]);
    __syncthreads();
    bf16x8 af[4], bfv[2];
#pragma unroll
    for (int i = 0; i < 4; i++) af[i] = *(const bf16x8*)&As[i * 16 + l15][l4 * 8];
#pragma unroll
    for (int i = 0; i < 2; i++) bfv[i] = *(const bf16x8*)&Bs[wv * 32 + i * 16 + l15][l4 * 8];
#pragma unroll
    for (int mi = 0; mi < 4; mi++)
#pragma unroll
      for (int ni = 0; ni < 2; ni++)
        acc[mi][ni] = __builtin_amdgcn_mfma_f32_16x16x32_bf16(af[mi], bfv[ni], acc[mi][ni], 0, 0, 0);
    __syncthreads();
  }
#pragma unroll
  for (int mi = 0; mi < 4; mi++)
#pragma unroll
    for (int ni = 0; ni < 2; ni++)
#pragma unroll
      for (int r = 0; r < 4; r++) {
        int m = m0 + mi * 16 + l4 * 4 + r;
        int n = n0 + wv * 32 + ni * 16 + l15;
        C[(size_t)m * DD + n] = acc[mi][ni][r];
      }
}

// ---------------- Vh [bh][s][d] -> VhT [bh][d][s]  (vlen skip) ----------------
__global__ __launch_bounds__(256) void vh_transpose(const bf16* __restrict__ Vh,
                                                    bf16* __restrict__ VhT,
                                                    const int* __restrict__ vlens) {
  __shared__ bf16 til[64][65];
  int bh = blockIdx.y;
  int s0 = blockIdx.x * 64;
  int vl = vlens[bh >> 4];
  if (vl > 0 && s0 >= vl + 32) return;
  const bf16* src = Vh + (size_t)bh * SS * DHH + (size_t)s0 * DHH;
  for (int i = threadIdx.x; i < 64 * 64; i += 256) {
    int r = i >> 6, cc = i & 63;
    til[r][cc] = src[(size_t)r * DHH + cc];
  }
  __syncthreads();
  bf16* dst = VhT + (size_t)bh * DHH * SS + s0;
  for (int i = threadIdx.x; i < 64 * 64; i += 256) {
    int d = i >> 6, cc = i & 63;
    dst[(size_t)d * SS + cc] = til[cc][d];
  }
}

// ---- fused attention: LDS-shared K/V tiles (4 waves, 1 bh), QR prologue, 4-mode softmax ----
// Ks[32][64] / Vs[64][32] staged once per block per tile via global_load_lds with
// PRE-SWIZZLED SOURCE (LDS linear): K chunk ^= row&7 (reads 2-way), V chunk ^= d&3 (4-way).
// Per-wave arena (10240 B): [0,4736) QRs 16x148 | [4736,8832) SBand 16x128 f16 |
// [8832,10112) Pl 16x40 bf16 -> li/a0/a128 floats in epilogue; AW 16x168 overlays [0,5376).
__global__ __launch_bounds__(256, 3) void attn_mfma(
    const bf16* __restrict__ Qh, const bf16* __restrict__ Kh, const bf16* __restrict__ VhT,
    const bf16* __restrict__ rkP, const int* __restrict__ valid_lens,
    const bf16* __restrict__ rvT, bf16* __restrict__ Obh) {
  __shared__ __align__(16) bf16 Ks[32][64];
  __shared__ __align__(16) bf16 Vs[64][32];
  __shared__ __align__(16) char arena[4][10240];
  const int tid = threadIdx.x, lane = tid & 63, w = tid >> 6;
  const int l15 = lane & 15, l4 = lane >> 4;
  const int b = blockIdx.z, h = blockIdx.y, bh = b * HH + h;
  const int q0 = blockIdx.x * 64 + w * 16;
  const int vlen = valid_lens[b];
  const float mval = (vlen == 0) ? 0.f : -30000.f;
  char* base = arena[w];
  bf16* QRs = (bf16*)base;                      // [16][148]
  _Float16* SBand = (_Float16*)(base + 4736);   // [16][128]
  bf16* Pl = (bf16*)(base + 8832);              // [16][40]

  const bf16* Qbase = Qh + ((size_t)bh * SS + q0) * DHH;
  bf16x8 qa0 = *(const bf16x8*)(Qbase + (size_t)l15 * DHH + l4 * 8);
  bf16x8 qa1 = *(const bf16x8*)(Qbase + (size_t)l15 * DHH + 32 + l4 * 8);
  const bf16* Kbase = Kh + (size_t)bh * SS * DHH;
  const bf16* Vbase = VhT + (size_t)bh * DHH * SS;
  f32x4 z = {0.f, 0.f, 0.f, 0.f};

  // ---- QR prologue: QRs[q][c] = Q[q]·rpr_k[c] via 9x2 MFMA on pre-packed bf16 rkP ----
#pragma unroll
  for (int ni = 0; ni < 9; ni++) {
    const bf16* rp = rkP + (size_t)(ni * 16 + l15) * DHH + l4 * 8;
    bf16x8 b0 = *(const bf16x8*)(rp);
    bf16x8 b1 = *(const bf16x8*)(rp + 32);
    f32x4 acc = __builtin_amdgcn_mfma_f32_16x16x32_bf16(qa0, b0, z, 0, 0, 0);
    acc = __builtin_amdgcn_mfma_f32_16x16x32_bf16(qa1, b1, acc, 0, 0, 0);
#pragma unroll
    for (int r = 0; r < 4; r++)
      QRs[(l4 * 4 + r) * QRSTR + ni * 16 + l15] = (bf16)acc[r];
  }
  {
    // SBand init: 4096 B = 256 x 16B; 4 b128 stores per lane
    const uint32_t nn = 0xFBFFFBFFu;  // -65504.f16 pair
    u32x4 vv = {nn, nn, nn, nn};
    u32x4* sb = (u32x4*)SBand;
#pragma unroll
    for (int i = 0; i < 4; i++) sb[lane + i * 64] = vv;
  }

  float biasLo[4], biasHi[4];
#pragma unroll
  for (int r = 0; r < 4; r++) {
    biasLo[r] = (float)QRs[(l4 * 4 + r) * QRSTR + 0];
    biasHi[r] = (float)QRs[(l4 * 4 + r) * QRSTR + 128];
  }

  float l_lane[4], slo[4], shi[4];
#pragma unroll
  for (int r = 0; r < 4; r++) { l_lane[r] = 0.f; slo[r] = 0.f; shi[r] = 0.f; }
  f32x4 acco[4];
#pragma unroll
  for (int i = 0; i < 4; i++) acco[i] = z;

  // swizzled LDS read offsets (elems)
  const int ksw0 = (l4 ^ (l15 & 7)) * 8;
  const int ksw1 = ((l4 + 4) ^ (l15 & 7)) * 8;
  const int vsw  = (l4 ^ (l15 & 3)) * 8;
  // staging constants (source pre-swizzle, LDS linear)
  const int krow = w * 8 + (lane >> 3);
  const int kch  = ((lane & 7) ^ (krow & 7)) * 8;
  const int vd   = w * 16 + (lane >> 2);
  const int vch  = ((lane & 3) ^ (vd & 3)) * 8;

  // bounds: tail tiles [kfb, kte); band [bs, be) for this wave's q0
  const int kfb = (vlen > 0) ? (vlen & ~31) : 0;
  const int kte = (vlen > 0) ? ((vlen + 31) & ~31) : SS;
  int bs = q0 - 94; bs = (bs < 0) ? 0 : ((bs + 31) & ~31);
  int be = (q0 + 110) & ~31; if (be > SS) be = SS;

  for (int ks = 0; ks < kte; ks += 32) {
    gload_lds16(Kbase + (size_t)(ks + krow) * DHH + kch, &Ks[w * 8][0]);
    gload_lds16(Vbase + (size_t)vd * SS + ks + vch, &Vs[w * 16][0]);
    __syncthreads();
    bf16x8 kf00 = *(const bf16x8*)&Ks[l15][ksw0];
    bf16x8 kf01 = *(const bf16x8*)&Ks[l15][ksw1];
    bf16x8 kf10 = *(const bf16x8*)&Ks[16 + l15][ksw0];
    bf16x8 kf11 = *(const bf16x8*)&Ks[16 + l15][ksw1];
    f32x4 a0 = __builtin_amdgcn_mfma_f32_16x16x32_bf16(qa0, kf00, z, 0, 0, 0);
    a0 = __builtin_amdgcn_mfma_f32_16x16x32_bf16(qa1, kf01, a0, 0, 0, 0);
    f32x4 a1 = __builtin_amdgcn_mfma_f32_16x16x32_bf16(qa0, kf10, z, 0, 0, 0);
    a1 = __builtin_amdgcn_mfma_f32_16x16x32_bf16(qa1, kf11, a1, 0, 0, 0);

    if (ks >= kfb) {
      // masked tail (<=1 tile for vlen>0; all tiles for vlen==0)
      const int rel = ks - q0;
      const int mode = (rel <= -95) ? 0 : (rel >= 79) ? 1 : 2;
#pragma unroll
      for (int sub = 0; sub < 2; sub++) {
        const f32x4 a = sub ? a1 : a0;
        const int kg = ks + sub * 16 + l15;
        const bool msk = (kg >= vlen);
        if (mode == 0) {
#pragma unroll
          for (int r = 0; r < 4; r++) {
            float s = msk ? mval : (a[r] + biasLo[r]);
            float p = __expf(s - M0F);
            l_lane[r] += p; slo[r] += p;
            Pl[(l4 * 4 + r) * 40 + sub * 16 + l15] = (bf16)p;
          }
        } else if (mode == 1) {
#pragma unroll
          for (int r = 0; r < 4; r++) {
            float s = msk ? mval : (a[r] + biasHi[r]);
            float p = __expf(s - M0F);
            l_lane[r] += p; shi[r] += p;
            Pl[(l4 * 4 + r) * 40 + sub * 16 + l15] = (bf16)p;
          }
        } else {
#pragma unroll
          for (int r = 0; r < 4; r++) {
            const int qloc = l4 * 4 + r;
            int dlt = kg - q0 - qloc;
            int c = (dlt < -NCLIP ? -NCLIP : (dlt > NCLIP ? NCLIP : dlt)) + NCLIP;
            float s = a[r] + (float)QRs[qloc * QRSTR + c];
            if (msk) s = mval;
            if (dlt > -64 && dlt < 64) SBand[qloc * 128 + dlt + 63] = (_Float16)s;
            float p = __expf(s - M0F);
            l_lane[r] += p;
            slo[r] += (dlt <= -64) ? p : 0.f;
            shi[r] += (dlt >= 64) ? p : 0.f;
            Pl[qloc * 40 + sub * 16 + l15] = (bf16)p;
          }
        }
      }
    } else if (ks < bs) {
      // lo tiles (all dlt <= -64, unmasked)
#pragma unroll
      for (int sub = 0; sub < 2; sub++) {
        const f32x4 a = sub ? a1 : a0;
#pragma unroll
        for (int r = 0; r < 4; r++) {
          float p = __expf(a[r] + biasLo[r] - M0F);
          l_lane[r] += p; slo[r] += p;
          Pl[(l4 * 4 + r) * 40 + sub * 16 + l15] = (bf16)p;
        }
      }
    } else if (ks < be) {
      // band tiles (unmasked, full body)
#pragma unroll
      for (int sub = 0; sub < 2; sub++) {
        const f32x4 a = sub ? a1 : a0;
        const int kg = ks + sub * 16 + l15;
#pragma unroll
        for (int r = 0; r < 4; r++) {
          const int qloc = l4 * 4 + r;
          int dlt = kg - q0 - qloc;
          int c = (dlt < -NCLIP ? -NCLIP : (dlt > NCLIP ? NCLIP : dlt)) + NCLIP;
          float s = a[r] + (float)QRs[qloc * QRSTR + c];
          if (dlt > -64 && dlt < 64) SBand[qloc * 128 + dlt + 63] = (_Float16)s;
          float p = __expf(s - M0F);
          l_lane[r] += p;
          slo[r] += (dlt <= -64) ? p : 0.f;
          shi[r] += (dlt >= 64) ? p : 0.f;
          Pl[qloc * 40 + sub * 16 + l15] = (bf16)p;
        }
      }
    } else {
      // hi tiles (all dlt >= 64, unmasked)
#pragma unroll
      for (int sub = 0; sub < 2; sub++) {
        const f32x4 a = sub ? a1 : a0;
#pragma unroll
        for (int r = 0; r < 4; r++) {
          float p = __expf(a[r] + biasHi[r] - M0F);
          l_lane[r] += p; shi[r] += p;
          Pl[(l4 * 4 + r) * 40 + sub * 16 + l15] = (bf16)p;
        }
      }
    }

    bf16x8 pa = *(const bf16x8*)&Pl[l15 * 40 + l4 * 8];
    acco[0] = __builtin_amdgcn_mfma_f32_16x16x32_bf16(pa, *(const bf16x8*)&Vs[l15][vsw], acco[0], 0, 0, 0);
    acco[1] = __builtin_amdgcn_mfma_f32_16x16x32_bf16(pa, *(const bf16x8*)&Vs[16 + l15][vsw], acco[1], 0, 0, 0);
    acco[2] = __builtin_amdgcn_mfma_f32_16x16x32_bf16(pa, *(const bf16x8*)&Vs[32 + l15][vsw], acco[2], 0, 0, 0);
    acco[3] = __builtin_amdgcn_mfma_f32_16x16x32_bf16(pa, *(const bf16x8*)&Vs[48 + l15][vsw], acco[3], 0, 0, 0);
    __syncthreads();
  }

  // ---- epilogue step 1: reduce l/slo/shi; stash li, aw0, aw128 ----
  float* li_s   = (float*)(base + 8832);
  float* a0_s   = (float*)(base + 8896);
  float* a128_s = (float*)(base + 8960);
  float li_r[4];
#pragma unroll
  for (int r = 0; r < 4; r++) {
    const int qloc = l4 * 4 + r;
    float lt = l_lane[r], so = slo[r], sh = shi[r];
    lt += __shfl_xor(lt, 1, 64); so += __shfl_xor(so, 1, 64); sh += __shfl_xor(sh, 1, 64);
    lt += __shfl_xor(lt, 2, 64); so += __shfl_xor(so, 2, 64); sh += __shfl_xor(sh, 2, 64);
    lt += __shfl_xor(lt, 4, 64); so += __shfl_xor(so, 4, 64); sh += __shfl_xor(sh, 4, 64);
    lt += __shfl_xor(lt, 8, 64); so += __shfl_xor(so, 8, 64); sh += __shfl_xor(sh, 8, 64);
    float li = 1.f / lt;
    li_r[r] = li;
    if (l15 == 0) { li_s[qloc] = li; a0_s[qloc] = so * li; a128_s[qloc] = sh * li; }
  }
  // ---- step 2: materialize AW 16x168 bf16 at arena[0] ----
  bf16* AWs = (bf16*)base;
  for (int row = 0; row < 16; row++) {
    float li = li_s[row], a0 = a0_s[row], a128 = a128_s[row];
#pragma unroll
    for (int j = 0; j < 3; j++) {
      int c = lane + 64 * j;
      if (c < 160) {
        float val;
        if (c == 0) val = a0;
        else if (c == 128) val = a128;
        else if (c < 128) val = __expf((float)SBand[row * 128 + c - 1] - M0F) * li;
        else val = 0.f;
        AWs[row * 168 + c] = (bf16)val;
      }
    }
  }
  // ---- step 3: acc2 = AW @ rpr_v ----
  f32x4 acc2[4];
#pragma unroll
  for (int i = 0; i < 4; i++) acc2[i] = z;
#pragma unroll
  for (int kk = 0; kk < 5; kk++) {
    bf16x8 af = *(const bf16x8*)&AWs[l15 * 168 + kk * 32 + l4 * 8];
#pragma unroll
    for (int ni = 0; ni < 4; ni++) {
      bf16x8 bv = *(const bf16x8*)(rvT + (size_t)(ni * 16 + l15) * NCP + kk * 32 + l4 * 8);
      acc2[ni] = __builtin_amdgcn_mfma_f32_16x16x32_bf16(af, bv, acc2[ni], 0, 0, 0);
    }
  }
  // ---- step 4: write Obh bf16 ----
#pragma unroll
  for (int ni = 0; ni < 4; ni++)
#pragma unroll
    for (int r = 0; r < 4; r++) {
      int qg = q0 + l4 * 4 + r;
      Obh[((size_t)b * SS + qg) * DD + h * DHH + ni * 16 + l15] =
          (bf16)(acco[ni][r] * li_r[r] + acc2[ni][r]);
    }
}

extern "C" void kernel_launch(void* const* d_in, const int* in_sizes, int n_in,
                              void* d_out, int out_size, void* d_ws, size_t ws_size,
                              hipStream_t stream) {
  (void)in_sizes; (void)n_in; (void)out_size; (void)ws_size;
  const float* queries = (const float*)d_in[0];
  const float* keys    = (const float*)d_in[1];
  const float* values  = (const float*)d_in[2];
  const int*   vlens   = (const int*)d_in[3];
  const float* Wq = (const float*)d_in[4];
  const float* Wk = (const float*)d_in[5];
  const float* Wv = (const float*)d_in[6];
  const float* Wo = (const float*)d_in[7];
  const float* rpr_k = (const float*)d_in[8];
  const float* rpr_v = (const float*)d_in[9];

  char* ws = (char*)d_ws;
  const size_t MB = 1024 * 1024;
  bf16* Wtq  = (bf16*)(ws + 0 * MB);
  bf16* Wtk  = (bf16*)(ws + 2 * MB);
  bf16* Wtv  = (bf16*)(ws + 4 * MB);
  bf16* Wto  = (bf16*)(ws + 6 * MB);
  bf16* Qh   = (bf16*)(ws + 8 * MB);    // head-split, scaled 0.125
  bf16* Kh   = (bf16*)(ws + 16 * MB);
  bf16* Vh   = (bf16*)(ws + 24 * MB);
  bf16* VhT  = (bf16*)(ws + 32 * MB);
  bf16* Qb   = (bf16*)(ws + 40 * MB);
  bf16* Kb   = (bf16*)(ws + 48 * MB);
  bf16* Vb   = (bf16*)(ws + 56 * MB);
  bf16* Obh  = (bf16*)(ws + 64 * MB);   // 8 MB
  bf16* rvT  = (bf16*)(ws + 72 * MB);   // 20 KB
  bf16* rkP  = (bf16*)(ws + 73 * MB);   // 18 KB

  TpArgs tp; tp.w[0] = Wq; tp.w[1] = Wk; tp.w[2] = Wv; tp.w[3] = Wo;
  tp.wt[0] = Wtq; tp.wt[1] = Wtk; tp.wt[2] = Wtv; tp.wt[3] = Wto;
  transpose_pack_w<<<dim3(32, 32, 4), dim3(32, 8), 0, stream>>>(tp);

  CvtArgs cv; cv.in[0] = queries; cv.in[1] = keys; cv.in[2] = values;
  cv.out[0] = Qb; cv.out[1] = Kb; cv.out[2] = Vb;
  cv.skip[0] = 0; cv.skip[1] = 1; cv.skip[2] = 1;
  cv.rpr_v = rpr_v; cv.rpr_k = rpr_k; cv.rvT = rvT; cv.rkP = rkP;
  f32_to_bf16_3<<<dim3(2048, 1, 4), 256, 0, stream>>>(cv, vlens);

  GemmArgs gp;
  gp.a[0] = Qb; gp.a[1] = Kb; gp.a[2] = Vb;
  gp.bt[0] = Wtq; gp.bt[1] = Wtk; gp.bt[2] = Wtv;
  gp.c[0] = (void*)Qh; gp.c[1] = (void*)Kh; gp.c[2] = (void*)Vh;
  gp.sc[0] = 0.125f; gp.sc[1] = 1.0f; gp.sc[2] = 1.0f;
  gp.skip[0] = 0; gp.skip[1] = 1; gp.skip[2] = 1;
  gemm128<true><<<dim3(8, 32, 3), 256, 0, stream>>>(gp, vlens);

  vh_transpose<<<dim3(16, 64), 256, 0, stream>>>(Vh, VhT, vlens);
  attn_mfma<<<dim3(16, HH, BB), 256, 0, stream>>>(Qh, Kh, VhT, rkP, vlens, rvT, Obh);
  gemm_bf16_final<<<dim3(8, 64), 256, 0, stream>>>(Obh, Wto, (float*)d_out);
}